// Round 1
// baseline (825.159 us; speedup 1.0000x reference)
//
#include <hip/hip_runtime.h>
#include <stdint.h>

static constexpr int kNU = 100000;
static constexpr int kNI = 50000;
static constexpr int kE  = 500000;
static constexpr int kC  = 128;
static constexpr int kB  = 1024;

__device__ __forceinline__ unsigned short f2bf(float f) {
  unsigned u = __float_as_uint(f);
  unsigned r = (u + 0x7fffu + ((u >> 16) & 1u)) >> 16;
  return (unsigned short)r;
}
__device__ __forceinline__ float bf2f(unsigned short h) {
  return __uint_as_float(((unsigned)h) << 16);
}

// ---- fp32 -> bf16 feature conversion (both tables in one launch) ----
__global__ void cvt_kernel(const float* __restrict__ xu, const float* __restrict__ xi,
                           unsigned short* __restrict__ fu, unsigned short* __restrict__ fi) {
  int i = blockIdx.x * blockDim.x + threadIdx.x;  // float4 index
  const int nu4 = kNU * kC / 4;
  const int ni4 = kNI * kC / 4;
  if (i < nu4) {
    float4 v = ((const float4*)xu)[i];
    ushort4 o; o.x = f2bf(v.x); o.y = f2bf(v.y); o.z = f2bf(v.z); o.w = f2bf(v.w);
    ((ushort4*)fu)[i] = o;
  } else if (i < nu4 + ni4) {
    int j = i - nu4;
    float4 v = ((const float4*)xi)[j];
    ushort4 o; o.x = f2bf(v.x); o.y = f2bf(v.y); o.z = f2bf(v.z); o.w = f2bf(v.w);
    ((ushort4*)fi)[j] = o;
  }
}

// ---- CSR build: histogram ----
__global__ void hist_kernel(const int* __restrict__ dui, const int* __restrict__ diu,
                            int* __restrict__ ci, int* __restrict__ cu) {
  int i = blockIdx.x * blockDim.x + threadIdx.x;
  if (i < kE) {
    atomicAdd(&ci[dui[i]], 1);
  } else if (i < 2 * kE) {
    atomicAdd(&cu[diu[i - kE]], 1);
  }
}

// ---- CSR build: 3-phase exclusive scan ----
__global__ void scan1_kernel(const int* __restrict__ c, int n, int* __restrict__ part) {
  __shared__ int s[256];
  int tid = threadIdx.x;
  int i = blockIdx.x * 256 + tid;
  s[tid] = (i < n) ? c[i] : 0;
  __syncthreads();
  for (int m = 128; m > 0; m >>= 1) {
    if (tid < m) s[tid] += s[tid + m];
    __syncthreads();
  }
  if (tid == 0) part[blockIdx.x] = s[0];
}

__global__ void scan2_kernel(int* __restrict__ part, int nb) {
  __shared__ int s[1024];
  int tid = threadIdx.x;
  int v = (tid < nb) ? part[tid] : 0;
  s[tid] = v;
  __syncthreads();
  for (int m = 1; m < 1024; m <<= 1) {
    int t = 0;
    if (tid >= m) t = s[tid - m];
    __syncthreads();
    s[tid] += t;
    __syncthreads();
  }
  if (tid < nb) part[tid] = s[tid] - v;  // exclusive
}

__global__ void scan3_kernel(const int* __restrict__ c, const int* __restrict__ part, int n,
                             int* __restrict__ rowptr, int* __restrict__ cursor) {
  __shared__ int s[256];
  int tid = threadIdx.x;
  int i = blockIdx.x * 256 + tid;
  int v = (i < n) ? c[i] : 0;
  s[tid] = v;
  __syncthreads();
  for (int m = 1; m < 256; m <<= 1) {
    int t = 0;
    if (tid >= m) t = s[tid - m];
    __syncthreads();
    s[tid] += t;
    __syncthreads();
  }
  int incl = s[tid];
  int excl = incl - v;
  int off = part[blockIdx.x];
  if (i < n) {
    rowptr[i] = off + excl;
    cursor[i] = off + excl;
    if (i == n - 1) rowptr[n] = off + incl;
  }
}

// ---- CSR build: bucket fill ----
__global__ void fill_kernel(const int* __restrict__ sui, const int* __restrict__ dui,
                            const int* __restrict__ siu, const int* __restrict__ diu,
                            int* __restrict__ cur_i, int* __restrict__ cur_u,
                            int* __restrict__ col_i, int* __restrict__ col_u) {
  int i = blockIdx.x * blockDim.x + threadIdx.x;
  if (i < kE) {
    int p = atomicAdd(&cur_i[dui[i]], 1);
    col_i[p] = sui[i];
  } else if (i < 2 * kE) {
    int e = i - kE;
    int p = atomicAdd(&cur_u[diu[e]], 1);
    col_u[p] = siu[e];
  }
}

// ---- atomic-free pull aggregation: one wave per dst node ----
__global__ void pull_kernel(const int* __restrict__ rowptr, const int* __restrict__ col,
                            const unsigned short* __restrict__ feat, float* __restrict__ agg,
                            int Nd) {
  int w = (blockIdx.x * blockDim.x + threadIdx.x) >> 6;
  int lane = threadIdx.x & 63;
  if (w >= Nd) return;
  int beg = rowptr[w], end = rowptr[w + 1];
  float a0 = 0.f, a1 = 0.f, b0 = 0.f, b1 = 0.f;
  int j = beg;
  for (; j + 1 < end; j += 2) {
    int s0 = col[j], s1 = col[j + 1];
    unsigned v0 = *(const unsigned*)(feat + s0 * kC + lane * 2);
    unsigned v1 = *(const unsigned*)(feat + s1 * kC + lane * 2);
    a0 += __uint_as_float(v0 << 16);
    a1 += __uint_as_float(v0 & 0xffff0000u);
    b0 += __uint_as_float(v1 << 16);
    b1 += __uint_as_float(v1 & 0xffff0000u);
  }
  if (j < end) {
    int s0 = col[j];
    unsigned v0 = *(const unsigned*)(feat + s0 * kC + lane * 2);
    a0 += __uint_as_float(v0 << 16);
    a1 += __uint_as_float(v0 & 0xffff0000u);
  }
  float2 r;
  r.x = a0 + b0;
  r.y = a1 + b1;
  *(float2*)&agg[w * kC + lane * 2] = r;
}

// ---- fused out = agg@Wr + feat@Wt + b; LayerNorm; ReLU; -> bf16 ----
// tile: 64 rows x 128 cols, 256 threads, per-thread 4 rows x 8 cols
__launch_bounds__(256)
__global__ void gemm_ln_kernel(const float* __restrict__ agg, const unsigned short* __restrict__ feat,
                               const float* __restrict__ Wr, const float* __restrict__ Wt,
                               const float* __restrict__ bias, const float* __restrict__ gamma,
                               const float* __restrict__ beta, unsigned short* __restrict__ out,
                               int N) {
  __shared__ float Al[32][68];   // A^T chunk, padded to keep 16B alignment
  __shared__ float Wl[32][128];  // W chunk
  int tid = threadIdx.x;
  int tx = tid & 15;        // 16 col groups
  int ty = tid >> 4;        // 16 row groups of 4
  int row0 = blockIdx.x * 64;

  float acc[4][8];
#pragma unroll
  for (int r = 0; r < 4; ++r)
#pragma unroll
    for (int j = 0; j < 8; ++j) acc[r][j] = 0.f;

  for (int p = 0; p < 2; ++p) {
    const float* W = p ? Wt : Wr;
    for (int kk = 0; kk < kC; kk += 32) {
      __syncthreads();
      // stage A^T (64 rows x 32 k)
#pragma unroll
      for (int i = 0; i < 8; ++i) {
        int idx = tid + i * 256;
        int r = idx >> 5, k = idx & 31;
        int gr = row0 + r;
        float v = 0.f;
        if (gr < N) v = p ? bf2f(feat[gr * kC + kk + k]) : agg[gr * kC + kk + k];
        Al[k][r] = v;
      }
      // stage W (32 k x 128 cols)
#pragma unroll
      for (int i = 0; i < 16; ++i) {
        int idx = tid + i * 256;
        int r = idx >> 7, c = idx & 127;
        Wl[r][c] = W[(kk + r) * kC + c];
      }
      __syncthreads();
#pragma unroll
      for (int k = 0; k < 32; ++k) {
        float4 a  = *(const float4*)&Al[k][ty * 4];
        float4 w0 = *(const float4*)&Wl[k][tx * 4];
        float4 w1 = *(const float4*)&Wl[k][64 + tx * 4];
        float av[4] = {a.x, a.y, a.z, a.w};
        float wv[8] = {w0.x, w0.y, w0.z, w0.w, w1.x, w1.y, w1.z, w1.w};
#pragma unroll
        for (int r = 0; r < 4; ++r)
#pragma unroll
          for (int j = 0; j < 8; ++j) acc[r][j] += av[r] * wv[j];
      }
    }
  }

  // epilogue: bias + LayerNorm (per row, 16-lane shuffle reduce) + ReLU
  float4 b0 = *(const float4*)&bias[tx * 4];
  float4 b1 = *(const float4*)&bias[64 + tx * 4];
  float4 g0 = *(const float4*)&gamma[tx * 4];
  float4 g1 = *(const float4*)&gamma[64 + tx * 4];
  float4 e0 = *(const float4*)&beta[tx * 4];
  float4 e1 = *(const float4*)&beta[64 + tx * 4];
  float bv[8] = {b0.x, b0.y, b0.z, b0.w, b1.x, b1.y, b1.z, b1.w};
  float gv[8] = {g0.x, g0.y, g0.z, g0.w, g1.x, g1.y, g1.z, g1.w};
  float ev[8] = {e0.x, e0.y, e0.z, e0.w, e1.x, e1.y, e1.z, e1.w};

#pragma unroll
  for (int r = 0; r < 4; ++r) {
    float s1 = 0.f, s2 = 0.f;
#pragma unroll
    for (int j = 0; j < 8; ++j) {
      float v = acc[r][j] + bv[j];
      acc[r][j] = v;
      s1 += v;
      s2 += v * v;
    }
#pragma unroll
    for (int m = 1; m < 16; m <<= 1) {
      s1 += __shfl_xor(s1, m, 64);
      s2 += __shfl_xor(s2, m, 64);
    }
    float mu = s1 * (1.f / 128.f);
    float var = s2 * (1.f / 128.f) - mu * mu;
    float rs = rsqrtf(var + 1e-5f);
    int gr = row0 + ty * 4 + r;
    if (gr < N) {
      unsigned short ov[8];
#pragma unroll
      for (int j = 0; j < 8; ++j) {
        float v = (acc[r][j] - mu) * rs * gv[j] + ev[j];
        v = fmaxf(v, 0.f);
        ov[j] = f2bf(v);
      }
      ushort4 o0; o0.x = ov[0]; o0.y = ov[1]; o0.z = ov[2]; o0.w = ov[3];
      ushort4 o1; o1.x = ov[4]; o1.y = ov[5]; o1.z = ov[6]; o1.w = ov[7];
      *(ushort4*)&out[gr * kC + tx * 4] = o0;
      *(ushort4*)&out[gr * kC + 64 + tx * 4] = o1;
    }
  }
}

// ---- final head: out[r] = feat_u[r,:] . lin_w + lin_b ----
__global__ void head_kernel(const unsigned short* __restrict__ fu, const float* __restrict__ lw,
                            const float* __restrict__ lb, float* __restrict__ out) {
  int w = (blockIdx.x * blockDim.x + threadIdx.x) >> 6;
  int lane = threadIdx.x & 63;
  if (w >= kB) return;
  unsigned v = *(const unsigned*)(fu + w * kC + lane * 2);
  float2 ww = *(const float2*)(lw + lane * 2);
  float p = __uint_as_float(v << 16) * ww.x + __uint_as_float(v & 0xffff0000u) * ww.y;
#pragma unroll
  for (int m = 1; m < 64; m <<= 1) p += __shfl_xor(p, m, 64);
  if (lane == 0) out[w] = p + lb[0];
}

extern "C" void kernel_launch(void* const* d_in, const int* in_sizes, int n_in,
                              void* d_out, int out_size, void* d_ws, size_t ws_size,
                              hipStream_t stream) {
  const float* x_user = (const float*)d_in[0];
  const float* x_item = (const float*)d_in[1];
  const int* e_ui_src = (const int*)d_in[2];
  const int* e_ui_dst = (const int*)d_in[3];
  const int* e_iu_src = (const int*)d_in[4];
  const int* e_iu_dst = (const int*)d_in[5];
  const float* w_rel  = (const float*)d_in[6];
  const float* w_root = (const float*)d_in[7];
  const float* bvec   = (const float*)d_in[8];
  const float* ln_g   = (const float*)d_in[9];
  const float* ln_b   = (const float*)d_in[10];
  const float* lin_w  = (const float*)d_in[11];
  const float* lin_b  = (const float*)d_in[12];

  char* p = (char*)d_ws;
  auto carve = [&](size_t bytes) -> char* {
    char* r = p;
    p += (bytes + 255) & ~size_t(255);
    return r;
  };
  unsigned short* fu[2] = {(unsigned short*)carve((size_t)kNU * kC * 2),
                           (unsigned short*)carve((size_t)kNU * kC * 2)};
  unsigned short* fi[2] = {(unsigned short*)carve((size_t)kNI * kC * 2),
                           (unsigned short*)carve((size_t)kNI * kC * 2)};
  float* agg    = (float*)carve((size_t)kNU * kC * 4);
  int* counts_i = (int*)carve((size_t)kNI * 4);
  int* counts_u = (int*)carve((size_t)kNU * 4);
  int* rowptr_i = (int*)carve((size_t)(kNI + 1) * 4);
  int* rowptr_u = (int*)carve((size_t)(kNU + 1) * 4);
  int* cursor_i = (int*)carve((size_t)kNI * 4);
  int* cursor_u = (int*)carve((size_t)kNU * 4);
  int* col_i    = (int*)carve((size_t)kE * 4);
  int* col_u    = (int*)carve((size_t)kE * 4);
  int* part_i   = (int*)carve(1024 * 4);
  int* part_u   = (int*)carve(1024 * 4);

  hipMemsetAsync(counts_i, 0, (size_t)kNI * 4, stream);
  hipMemsetAsync(counts_u, 0, (size_t)kNU * 4, stream);

  int cvtN = (kNU * kC + kNI * kC) / 4;
  cvt_kernel<<<(cvtN + 255) / 256, 256, 0, stream>>>(x_user, x_item, fu[0], fi[0]);

  hist_kernel<<<(2 * kE + 255) / 256, 256, 0, stream>>>(e_ui_dst, e_iu_dst, counts_i, counts_u);

  int nbi = (kNI + 255) / 256;
  int nbu = (kNU + 255) / 256;
  scan1_kernel<<<nbi, 256, 0, stream>>>(counts_i, kNI, part_i);
  scan1_kernel<<<nbu, 256, 0, stream>>>(counts_u, kNU, part_u);
  scan2_kernel<<<1, 1024, 0, stream>>>(part_i, nbi);
  scan2_kernel<<<1, 1024, 0, stream>>>(part_u, nbu);
  scan3_kernel<<<nbi, 256, 0, stream>>>(counts_i, part_i, kNI, rowptr_i, cursor_i);
  scan3_kernel<<<nbu, 256, 0, stream>>>(counts_u, part_u, kNU, rowptr_u, cursor_u);

  fill_kernel<<<(2 * kE + 255) / 256, 256, 0, stream>>>(e_ui_src, e_ui_dst, e_iu_src, e_iu_dst,
                                                        cursor_i, cursor_u, col_i, col_u);

  int cur = 0;
  for (int l = 0; l < 2; ++l) {
    // user -> item
    pull_kernel<<<(kNI + 3) / 4, 256, 0, stream>>>(rowptr_i, col_i, fu[cur], agg, kNI);
    gemm_ln_kernel<<<(kNI + 63) / 64, 256, 0, stream>>>(
        agg, fi[cur], w_rel + (size_t)(l * 2 + 0) * kC * kC, w_root + (size_t)(l * 2 + 0) * kC * kC,
        bvec + (size_t)(l * 2 + 0) * kC, ln_g + (size_t)(l * 2 + 1) * kC,
        ln_b + (size_t)(l * 2 + 1) * kC, fi[1 - cur], kNI);
    // item -> user (fi[cur] still the layer-l input)
    pull_kernel<<<(kNU + 3) / 4, 256, 0, stream>>>(rowptr_u, col_u, fi[cur], agg, kNU);
    gemm_ln_kernel<<<(kNU + 63) / 64, 256, 0, stream>>>(
        agg, fu[cur], w_rel + (size_t)(l * 2 + 1) * kC * kC, w_root + (size_t)(l * 2 + 1) * kC * kC,
        bvec + (size_t)(l * 2 + 1) * kC, ln_g + (size_t)(l * 2 + 0) * kC,
        ln_b + (size_t)(l * 2 + 0) * kC, fu[1 - cur], kNU);
    cur ^= 1;
  }

  head_kernel<<<(kB + 3) / 4, 256, 0, stream>>>(fu[cur], lin_w, lin_b, (float*)d_out);
}

// Round 2
// 500.307 us; speedup vs baseline: 1.6493x; 1.6493x over previous
//
#include <hip/hip_runtime.h>
#include <stdint.h>

static constexpr int kNU = 100000;
static constexpr int kNI = 50000;
static constexpr int kE  = 500000;
static constexpr int kC  = 128;
static constexpr int kB  = 1024;

typedef __attribute__((ext_vector_type(8))) short bf16x8;
typedef __attribute__((ext_vector_type(4))) float f32x4;

__device__ __forceinline__ unsigned short f2bf(float f) {
  unsigned u = __float_as_uint(f);
  unsigned r = (u + 0x7fffu + ((u >> 16) & 1u)) >> 16;
  return (unsigned short)r;
}
__device__ __forceinline__ float bf2f(unsigned short h) {
  return __uint_as_float(((unsigned)h) << 16);
}

// ---- fp32 -> bf16 feature conversion (both tables in one launch) ----
__global__ void cvt_kernel(const float* __restrict__ xu, const float* __restrict__ xi,
                           unsigned short* __restrict__ fu, unsigned short* __restrict__ fi) {
  int i = blockIdx.x * blockDim.x + threadIdx.x;  // float4 index
  const int nu4 = kNU * kC / 4;
  const int ni4 = kNI * kC / 4;
  if (i < nu4) {
    float4 v = ((const float4*)xu)[i];
    ushort4 o; o.x = f2bf(v.x); o.y = f2bf(v.y); o.z = f2bf(v.z); o.w = f2bf(v.w);
    ((ushort4*)fu)[i] = o;
  } else if (i < nu4 + ni4) {
    int j = i - nu4;
    float4 v = ((const float4*)xi)[j];
    ushort4 o; o.x = f2bf(v.x); o.y = f2bf(v.y); o.z = f2bf(v.z); o.w = f2bf(v.w);
    ((ushort4*)fi)[j] = o;
  }
}

// ---- weight prep: wcat[m][n][k] bf16, m = l*2+t; k<128 -> w_rel^T, k>=128 -> w_root^T ----
__global__ void prep_w_kernel(const float* __restrict__ wrel, const float* __restrict__ wroot,
                              unsigned short* __restrict__ wcat) {
  int id = blockIdx.x * 256 + threadIdx.x;  // 4*128*256 = 131072
  int m = id >> 15;
  int n = (id >> 8) & 127;
  int k = id & 255;
  float v = (k < 128) ? wrel[(m * 128 + k) * 128 + n] : wroot[(m * 128 + (k - 128)) * 128 + n];
  wcat[id] = f2bf(v);
}

// ---- CSR build: histogram ----
__global__ void hist_kernel(const int* __restrict__ dui, const int* __restrict__ diu,
                            int* __restrict__ ci, int* __restrict__ cu) {
  int i = blockIdx.x * blockDim.x + threadIdx.x;
  if (i < kE) {
    atomicAdd(&ci[dui[i]], 1);
  } else if (i < 2 * kE) {
    atomicAdd(&cu[diu[i - kE]], 1);
  }
}

// ---- CSR build: 3-phase exclusive scan ----
__global__ void scan1_kernel(const int* __restrict__ c, int n, int* __restrict__ part) {
  __shared__ int s[256];
  int tid = threadIdx.x;
  int i = blockIdx.x * 256 + tid;
  s[tid] = (i < n) ? c[i] : 0;
  __syncthreads();
  for (int m = 128; m > 0; m >>= 1) {
    if (tid < m) s[tid] += s[tid + m];
    __syncthreads();
  }
  if (tid == 0) part[blockIdx.x] = s[0];
}

__global__ void scan2_kernel(int* __restrict__ part, int nb) {
  __shared__ int s[1024];
  int tid = threadIdx.x;
  int v = (tid < nb) ? part[tid] : 0;
  s[tid] = v;
  __syncthreads();
  for (int m = 1; m < 1024; m <<= 1) {
    int t = 0;
    if (tid >= m) t = s[tid - m];
    __syncthreads();
    s[tid] += t;
    __syncthreads();
  }
  if (tid < nb) part[tid] = s[tid] - v;  // exclusive
}

__global__ void scan3_kernel(const int* __restrict__ c, const int* __restrict__ part, int n,
                             int* __restrict__ rowptr, int* __restrict__ cursor) {
  __shared__ int s[256];
  int tid = threadIdx.x;
  int i = blockIdx.x * 256 + tid;
  int v = (i < n) ? c[i] : 0;
  s[tid] = v;
  __syncthreads();
  for (int m = 1; m < 256; m <<= 1) {
    int t = 0;
    if (tid >= m) t = s[tid - m];
    __syncthreads();
    s[tid] += t;
    __syncthreads();
  }
  int incl = s[tid];
  int excl = incl - v;
  int off = part[blockIdx.x];
  if (i < n) {
    rowptr[i] = off + excl;
    cursor[i] = off + excl;
    if (i == n - 1) rowptr[n] = off + incl;
  }
}

// ---- CSR build: bucket fill ----
__global__ void fill_kernel(const int* __restrict__ sui, const int* __restrict__ dui,
                            const int* __restrict__ siu, const int* __restrict__ diu,
                            int* __restrict__ cur_i, int* __restrict__ cur_u,
                            int* __restrict__ col_i, int* __restrict__ col_u) {
  int i = blockIdx.x * blockDim.x + threadIdx.x;
  if (i < kE) {
    int p = atomicAdd(&cur_i[dui[i]], 1);
    col_i[p] = sui[i];
  } else if (i < 2 * kE) {
    int e = i - kE;
    int p = atomicAdd(&cur_u[diu[e]], 1);
    col_u[p] = siu[e];
  }
}

// ---- atomic-free pull aggregation: one wave per dst node, bf16 out ----
__global__ void pull_kernel(const int* __restrict__ rowptr, const int* __restrict__ col,
                            const unsigned short* __restrict__ feat,
                            unsigned short* __restrict__ agg, int Nd) {
  int w = (blockIdx.x * blockDim.x + threadIdx.x) >> 6;
  int lane = threadIdx.x & 63;
  if (w >= Nd) return;
  int beg = rowptr[w], end = rowptr[w + 1];
  float a0 = 0.f, a1 = 0.f, b0 = 0.f, b1 = 0.f;
  int j = beg;
  for (; j + 1 < end; j += 2) {
    int s0 = col[j], s1 = col[j + 1];
    unsigned v0 = *(const unsigned*)(feat + s0 * kC + lane * 2);
    unsigned v1 = *(const unsigned*)(feat + s1 * kC + lane * 2);
    a0 += __uint_as_float(v0 << 16);
    a1 += __uint_as_float(v0 & 0xffff0000u);
    b0 += __uint_as_float(v1 << 16);
    b1 += __uint_as_float(v1 & 0xffff0000u);
  }
  if (j < end) {
    int s0 = col[j];
    unsigned v0 = *(const unsigned*)(feat + s0 * kC + lane * 2);
    a0 += __uint_as_float(v0 << 16);
    a1 += __uint_as_float(v0 & 0xffff0000u);
  }
  unsigned rw = (unsigned)f2bf(a0 + b0) | ((unsigned)f2bf(a1 + b1) << 16);
  ((unsigned*)agg)[w * 64 + lane] = rw;
}

// ---- MFMA GEMM: out = LN([agg|feat] @ wcat^T(+bias)) relu -> bf16 ----
// block: 128 rows x 128 cols, 256 threads = 4 waves; wave w -> rows [w*32, w*32+32)
// per wave: 2 (m) x 8 (n) frags of 16x16, K-loop 8 steps of 32
__launch_bounds__(256)
__global__ void gemm_ln_kernel(const unsigned short* __restrict__ agg,
                               const unsigned short* __restrict__ feat,
                               const unsigned short* __restrict__ wcat,  // [128 n][256 k] bf16
                               const float* __restrict__ bias, const float* __restrict__ gamma,
                               const float* __restrict__ beta, unsigned short* __restrict__ out,
                               int N) {
  __shared__ unsigned short As[128 * 32];  // [row][k] 64 B/row
  __shared__ unsigned short Ws[128 * 32];  // [n][k]   64 B/row
  int tid = threadIdx.x;
  int lane = tid & 63;
  int wv = tid >> 6;
  int q = lane >> 4;
  int c0 = lane & 15;
  int row0 = blockIdx.x * 128;

  f32x4 acc[2][8];
#pragma unroll
  for (int mt = 0; mt < 2; ++mt)
#pragma unroll
    for (int nt = 0; nt < 8; ++nt) acc[mt][nt] = (f32x4){0.f, 0.f, 0.f, 0.f};

#pragma unroll
  for (int ks = 0; ks < 8; ++ks) {
    int kk = ks * 32;
    const unsigned short* Asrc = (kk < 128) ? agg : feat;
    int kcol = kk & 127;
    __syncthreads();
    // stage A: 128 rows x 32 k (8 KB) — 512 chunks of 16 B, 2 per thread
#pragma unroll
    for (int i = 0; i < 2; ++i) {
      int c = tid + i * 256;
      int r = c >> 2, part = c & 3;
      int gr = row0 + r;
      int4 v = {0, 0, 0, 0};
      if (gr < N) v = *(const int4*)(Asrc + (size_t)gr * kC + kcol + part * 8);
      *(int4*)&As[r * 32 + part * 8] = v;
    }
    // stage W^T: 128 n x 32 k
#pragma unroll
    for (int i = 0; i < 2; ++i) {
      int c = tid + i * 256;
      int r = c >> 2, part = c & 3;
      int4 v = *(const int4*)(wcat + r * 256 + kk + part * 8);
      *(int4*)&Ws[r * 32 + part * 8] = v;
    }
    __syncthreads();

    bf16x8 a0 = *(const bf16x8*)&As[(wv * 32 + c0) * 32 + q * 8];
    bf16x8 a1 = *(const bf16x8*)&As[(wv * 32 + 16 + c0) * 32 + q * 8];
#pragma unroll
    for (int nt = 0; nt < 8; ++nt) {
      bf16x8 b = *(const bf16x8*)&Ws[(nt * 16 + c0) * 32 + q * 8];
      acc[0][nt] = __builtin_amdgcn_mfma_f32_16x16x32_bf16(a0, b, acc[0][nt], 0, 0, 0);
      acc[1][nt] = __builtin_amdgcn_mfma_f32_16x16x32_bf16(a1, b, acc[1][nt], 0, 0, 0);
    }
  }

  // epilogue: per-row LN across 128 cols. C/D layout: col = c0, row = q*4+reg.
  // All 16 lanes of a quad hold the same row -> xor-shuffle {1,2,4,8} reduces the row.
  float bcol[8], gcol[8], ecol[8];
#pragma unroll
  for (int nt = 0; nt < 8; ++nt) {
    bcol[nt] = bias[nt * 16 + c0];
    gcol[nt] = gamma[nt * 16 + c0];
    ecol[nt] = beta[nt * 16 + c0];
  }
  int rbase = row0 + wv * 32;
#pragma unroll
  for (int mt = 0; mt < 2; ++mt) {
#pragma unroll
    for (int reg = 0; reg < 4; ++reg) {
      int row = rbase + mt * 16 + q * 4 + reg;
      float v[8];
      float s1 = 0.f, s2 = 0.f;
#pragma unroll
      for (int nt = 0; nt < 8; ++nt) {
        float t = acc[mt][nt][reg] + bcol[nt];
        v[nt] = t;
        s1 += t;
        s2 += t * t;
      }
#pragma unroll
      for (int m = 1; m < 16; m <<= 1) {
        s1 += __shfl_xor(s1, m, 64);
        s2 += __shfl_xor(s2, m, 64);
      }
      float mu = s1 * (1.f / 128.f);
      float var = s2 * (1.f / 128.f) - mu * mu;
      float rs = rsqrtf(var + 1e-5f);
      if (row < N) {
#pragma unroll
        for (int nt = 0; nt < 8; ++nt) {
          float o = fmaxf((v[nt] - mu) * rs * gcol[nt] + ecol[nt], 0.f);
          unsigned short h = f2bf(o);
          unsigned up = __shfl_xor((unsigned)h, 1, 64);
          if ((lane & 1) == 0) {
            *(unsigned*)(out + (size_t)row * kC + nt * 16 + c0) = (unsigned)h | (up << 16);
          }
        }
      }
    }
  }
}

// ---- final head: out[r] = feat_u[r,:] . lin_w + lin_b ----
__global__ void head_kernel(const unsigned short* __restrict__ fu, const float* __restrict__ lw,
                            const float* __restrict__ lb, float* __restrict__ out) {
  int w = (blockIdx.x * blockDim.x + threadIdx.x) >> 6;
  int lane = threadIdx.x & 63;
  if (w >= kB) return;
  unsigned v = *(const unsigned*)(fu + w * kC + lane * 2);
  float2 ww = *(const float2*)(lw + lane * 2);
  float p = __uint_as_float(v << 16) * ww.x + __uint_as_float(v & 0xffff0000u) * ww.y;
#pragma unroll
  for (int m = 1; m < 64; m <<= 1) p += __shfl_xor(p, m, 64);
  if (lane == 0) out[w] = p + lb[0];
}

extern "C" void kernel_launch(void* const* d_in, const int* in_sizes, int n_in,
                              void* d_out, int out_size, void* d_ws, size_t ws_size,
                              hipStream_t stream) {
  const float* x_user = (const float*)d_in[0];
  const float* x_item = (const float*)d_in[1];
  const int* e_ui_src = (const int*)d_in[2];
  const int* e_ui_dst = (const int*)d_in[3];
  const int* e_iu_src = (const int*)d_in[4];
  const int* e_iu_dst = (const int*)d_in[5];
  const float* w_rel  = (const float*)d_in[6];
  const float* w_root = (const float*)d_in[7];
  const float* bvec   = (const float*)d_in[8];
  const float* ln_g   = (const float*)d_in[9];
  const float* ln_b   = (const float*)d_in[10];
  const float* lin_w  = (const float*)d_in[11];
  const float* lin_b  = (const float*)d_in[12];

  char* p = (char*)d_ws;
  auto carve = [&](size_t bytes) -> char* {
    char* r = p;
    p += (bytes + 255) & ~size_t(255);
    return r;
  };
  unsigned short* fu[2] = {(unsigned short*)carve((size_t)kNU * kC * 2),
                           (unsigned short*)carve((size_t)kNU * kC * 2)};
  unsigned short* fi[2] = {(unsigned short*)carve((size_t)kNI * kC * 2),
                           (unsigned short*)carve((size_t)kNI * kC * 2)};
  unsigned short* agg  = (unsigned short*)carve((size_t)kNU * kC * 2);
  unsigned short* wcat = (unsigned short*)carve((size_t)4 * 128 * 256 * 2);
  int* counts_i = (int*)carve((size_t)kNI * 4);
  int* counts_u = (int*)carve((size_t)kNU * 4);
  int* rowptr_i = (int*)carve((size_t)(kNI + 1) * 4);
  int* rowptr_u = (int*)carve((size_t)(kNU + 1) * 4);
  int* cursor_i = (int*)carve((size_t)kNI * 4);
  int* cursor_u = (int*)carve((size_t)kNU * 4);
  int* col_i    = (int*)carve((size_t)kE * 4);
  int* col_u    = (int*)carve((size_t)kE * 4);
  int* part_i   = (int*)carve(1024 * 4);
  int* part_u   = (int*)carve(1024 * 4);

  hipMemsetAsync(counts_i, 0, (size_t)kNI * 4, stream);
  hipMemsetAsync(counts_u, 0, (size_t)kNU * 4, stream);

  int cvtN = (kNU * kC + kNI * kC) / 4;
  cvt_kernel<<<(cvtN + 255) / 256, 256, 0, stream>>>(x_user, x_item, fu[0], fi[0]);
  prep_w_kernel<<<512, 256, 0, stream>>>(w_rel, w_root, wcat);

  hist_kernel<<<(2 * kE + 255) / 256, 256, 0, stream>>>(e_ui_dst, e_iu_dst, counts_i, counts_u);

  int nbi = (kNI + 255) / 256;
  int nbu = (kNU + 255) / 256;
  scan1_kernel<<<nbi, 256, 0, stream>>>(counts_i, kNI, part_i);
  scan1_kernel<<<nbu, 256, 0, stream>>>(counts_u, kNU, part_u);
  scan2_kernel<<<1, 1024, 0, stream>>>(part_i, nbi);
  scan2_kernel<<<1, 1024, 0, stream>>>(part_u, nbu);
  scan3_kernel<<<nbi, 256, 0, stream>>>(counts_i, part_i, kNI, rowptr_i, cursor_i);
  scan3_kernel<<<nbu, 256, 0, stream>>>(counts_u, part_u, kNU, rowptr_u, cursor_u);

  fill_kernel<<<(2 * kE + 255) / 256, 256, 0, stream>>>(e_ui_src, e_ui_dst, e_iu_src, e_iu_dst,
                                                        cursor_i, cursor_u, col_i, col_u);

  int cur = 0;
  for (int l = 0; l < 2; ++l) {
    // user -> item
    pull_kernel<<<(kNI + 3) / 4, 256, 0, stream>>>(rowptr_i, col_i, fu[cur], agg, kNI);
    gemm_ln_kernel<<<(kNI + 127) / 128, 256, 0, stream>>>(
        agg, fi[cur], wcat + (size_t)(l * 2 + 0) * 128 * 256,
        bvec + (size_t)(l * 2 + 0) * kC, ln_g + (size_t)(l * 2 + 1) * kC,
        ln_b + (size_t)(l * 2 + 1) * kC, fi[1 - cur], kNI);
    // item -> user (fi[cur] still the layer-l input)
    pull_kernel<<<(kNU + 3) / 4, 256, 0, stream>>>(rowptr_u, col_u, fi[cur], agg, kNU);
    gemm_ln_kernel<<<(kNU + 127) / 128, 256, 0, stream>>>(
        agg, fu[cur], wcat + (size_t)(l * 2 + 1) * 128 * 256,
        bvec + (size_t)(l * 2 + 1) * kC, ln_g + (size_t)(l * 2 + 0) * kC,
        ln_b + (size_t)(l * 2 + 0) * kC, fu[1 - cur], kNU);
    cur ^= 1;
  }

  head_kernel<<<(kB + 3) / 4, 256, 0, stream>>>(fu[cur], lin_w, lin_b, (float*)d_out);
}

// Round 3
// 475.648 us; speedup vs baseline: 1.7348x; 1.0518x over previous
//
#include <hip/hip_runtime.h>
#include <stdint.h>

static constexpr int kNU = 100000;
static constexpr int kNI = 50000;
static constexpr int kE  = 500000;
static constexpr int kC  = 128;
static constexpr int kB  = 1024;
static constexpr int kNBK = 64;   // binning blocks
static constexpr int kCap = 4096; // max edges per coarse bucket (mean 2560, sigma ~51)

typedef __attribute__((ext_vector_type(8))) short bf16x8;
typedef __attribute__((ext_vector_type(4))) float f32x4;

__device__ __forceinline__ unsigned short f2bf(float f) {
  unsigned u = __float_as_uint(f);
  unsigned r = (u + 0x7fffu + ((u >> 16) & 1u)) >> 16;
  return (unsigned short)r;
}
__device__ __forceinline__ float bf2f(unsigned short h) {
  return __uint_as_float(((unsigned)h) << 16);
}

// ---- fp32 -> bf16 feature conversion (both tables in one launch) ----
__global__ void cvt_kernel(const float* __restrict__ xu, const float* __restrict__ xi,
                           unsigned short* __restrict__ fu, unsigned short* __restrict__ fi) {
  int i = blockIdx.x * blockDim.x + threadIdx.x;  // float4 index
  const int nu4 = kNU * kC / 4;
  const int ni4 = kNI * kC / 4;
  if (i < nu4) {
    float4 v = ((const float4*)xu)[i];
    ushort4 o; o.x = f2bf(v.x); o.y = f2bf(v.y); o.z = f2bf(v.z); o.w = f2bf(v.w);
    ((ushort4*)fu)[i] = o;
  } else if (i < nu4 + ni4) {
    int j = i - nu4;
    float4 v = ((const float4*)xi)[j];
    ushort4 o; o.x = f2bf(v.x); o.y = f2bf(v.y); o.z = f2bf(v.z); o.w = f2bf(v.w);
    ((ushort4*)fi)[j] = o;
  }
}

// ---- weight prep: wcat[m][n][k] bf16, m = l*2+t; k<128 -> w_rel^T, k>=128 -> w_root^T ----
__global__ void prep_w_kernel(const float* __restrict__ wrel, const float* __restrict__ wroot,
                              unsigned short* __restrict__ wcat) {
  int id = blockIdx.x * 256 + threadIdx.x;  // 4*128*256 = 131072
  int m = id >> 15;
  int n = (id >> 8) & 127;
  int k = id & 255;
  float v = (k < 128) ? wrel[(m * 128 + k) * 128 + n] : wroot[(m * 128 + (k - 128)) * 128 + n];
  wcat[id] = f2bf(v);
}

// ================= LDS-binned CSR build (no global atomics) =================
// Coarse bucket = dst >> shift (196 used buckets, padded to 256).
// A: per-block LDS histogram over buckets
__global__ void binA_kernel(const int* __restrict__ dst, int shift, int* __restrict__ bh) {
  __shared__ int h[256];
  int tid = threadIdx.x;
  h[tid] = 0;
  __syncthreads();
  int chunk = (kE + kNBK - 1) / kNBK;
  int beg = blockIdx.x * chunk;
  int end = min(kE, beg + chunk);
  for (int i = beg + tid; i < end; i += 256) atomicAdd(&h[dst[i] >> shift], 1);
  __syncthreads();
  bh[blockIdx.x * 256 + tid] = h[tid];
}

// B: per-(block,bucket) offsets + bucket bases
__global__ void binB_kernel(const int* __restrict__ bh, int* __restrict__ bo,
                            int* __restrict__ base) {
  __shared__ int s[256];
  int t = threadIdx.x;
  int run = 0;
  for (int b = 0; b < kNBK; ++b) {
    int v = bh[b * 256 + t];
    bo[b * 256 + t] = run;
    run += v;
  }
  s[t] = run;
  __syncthreads();
  for (int m = 1; m < 256; m <<= 1) {  // inclusive scan
    int tv = 0;
    if (t >= m) tv = s[t - m];
    __syncthreads();
    s[t] += tv;
    __syncthreads();
  }
  base[t] = s[t] - run;  // exclusive
  if (t == 255) base[256] = s[255];
}

// C: scatter packed (src | local_dst<<17) into bucket segments via LDS cursors
__global__ void binC_kernel(const int* __restrict__ src, const int* __restrict__ dst, int shift,
                            const int* __restrict__ bo, const int* __restrict__ base,
                            unsigned* __restrict__ packed) {
  __shared__ int cur[256];
  int tid = threadIdx.x;
  cur[tid] = base[tid] + bo[blockIdx.x * 256 + tid];
  __syncthreads();
  int chunk = (kE + kNBK - 1) / kNBK;
  int beg = blockIdx.x * chunk;
  int end = min(kE, beg + chunk);
  int mask = (1 << shift) - 1;
  for (int i = beg + tid; i < end; i += 256) {
    int d = dst[i];
    int p = atomicAdd(&cur[d >> shift], 1);
    packed[p] = (unsigned)src[i] | ((unsigned)(d & mask) << 17);
  }
}

// D: in-LDS counting sort of one bucket by fine dst; emit col + rowptr
__launch_bounds__(256)
__global__ void binD_kernel(const unsigned* __restrict__ packed, const int* __restrict__ base,
                            int bsize, int Nd, int* __restrict__ col, int* __restrict__ rowptr) {
  __shared__ unsigned ent[kCap];
  __shared__ int srt[kCap];
  __shared__ int hist[512];
  __shared__ int cur[512];
  int tid = threadIdx.x;
  int bb = blockIdx.x;
  int seg_beg = base[bb], seg_end = base[bb + 1];
  int cnt = seg_end - seg_beg;
  if (cnt > kCap) cnt = kCap;  // ~30-sigma guard, never triggers for this data
  hist[tid] = 0;
  hist[tid + 256] = 0;
  __syncthreads();
  for (int i = tid; i < cnt; i += 256) {
    unsigned e = packed[seg_beg + i];
    ent[i] = e;
    atomicAdd(&hist[e >> 17], 1);
  }
  __syncthreads();
  // Blelloch exclusive scan over 512 with 256 threads
  for (int d = 1; d < 512; d <<= 1) {
    int idx = (tid + 1) * 2 * d - 1;
    if (idx < 512) hist[idx] += hist[idx - d];
    __syncthreads();
  }
  if (tid == 0) hist[511] = 0;
  __syncthreads();
  for (int d = 256; d >= 1; d >>= 1) {
    int idx = (tid + 1) * 2 * d - 1;
    if (idx < 512) {
      int tmp = hist[idx - d];
      hist[idx - d] = hist[idx];
      hist[idx] += tmp;
    }
    __syncthreads();
  }
  // rowptr for this bucket's nodes
  for (int j = tid; j < bsize; j += 256) {
    int n = bb * bsize + j;
    if (n < Nd) rowptr[n] = seg_beg + hist[j];
  }
  if (bb == gridDim.x - 1 && tid == 0) rowptr[Nd] = seg_end;
  cur[tid] = hist[tid];
  cur[tid + 256] = hist[tid + 256];
  __syncthreads();
  for (int i = tid; i < cnt; i += 256) {
    unsigned e = ent[i];
    int p = atomicAdd(&cur[e >> 17], 1);
    srt[p] = (int)(e & 0x1FFFFu);
  }
  __syncthreads();
  for (int i = tid; i < cnt; i += 256) col[seg_beg + i] = srt[i];
}

// ---- atomic-free pull aggregation: one wave per dst node, bf16 out, 4-deep ILP ----
__global__ void pull_kernel(const int* __restrict__ rowptr, const int* __restrict__ col,
                            const unsigned short* __restrict__ feat,
                            unsigned short* __restrict__ agg, int Nd) {
  int w = (blockIdx.x * blockDim.x + threadIdx.x) >> 6;
  int lane = threadIdx.x & 63;
  if (w >= Nd) return;
  int beg = rowptr[w], end = rowptr[w + 1];
  float a0 = 0.f, a1 = 0.f, b0 = 0.f, b1 = 0.f;
  float c0 = 0.f, c1 = 0.f, d0 = 0.f, d1 = 0.f;
  int j = beg;
  for (; j + 3 < end; j += 4) {
    int s0 = col[j], s1 = col[j + 1], s2 = col[j + 2], s3 = col[j + 3];
    unsigned v0 = *(const unsigned*)(feat + s0 * kC + lane * 2);
    unsigned v1 = *(const unsigned*)(feat + s1 * kC + lane * 2);
    unsigned v2 = *(const unsigned*)(feat + s2 * kC + lane * 2);
    unsigned v3 = *(const unsigned*)(feat + s3 * kC + lane * 2);
    a0 += __uint_as_float(v0 << 16);
    a1 += __uint_as_float(v0 & 0xffff0000u);
    b0 += __uint_as_float(v1 << 16);
    b1 += __uint_as_float(v1 & 0xffff0000u);
    c0 += __uint_as_float(v2 << 16);
    c1 += __uint_as_float(v2 & 0xffff0000u);
    d0 += __uint_as_float(v3 << 16);
    d1 += __uint_as_float(v3 & 0xffff0000u);
  }
  for (; j < end; ++j) {
    int s0 = col[j];
    unsigned v0 = *(const unsigned*)(feat + s0 * kC + lane * 2);
    a0 += __uint_as_float(v0 << 16);
    a1 += __uint_as_float(v0 & 0xffff0000u);
  }
  float r0 = (a0 + b0) + (c0 + d0);
  float r1 = (a1 + b1) + (c1 + d1);
  unsigned rw = (unsigned)f2bf(r0) | ((unsigned)f2bf(r1) << 16);
  ((unsigned*)agg)[w * 64 + lane] = rw;
}

// ---- MFMA GEMM: out = LN([agg|feat] @ wcat^T(+bias)) relu -> bf16 ----
__launch_bounds__(256)
__global__ void gemm_ln_kernel(const unsigned short* __restrict__ agg,
                               const unsigned short* __restrict__ feat,
                               const unsigned short* __restrict__ wcat,  // [128 n][256 k] bf16
                               const float* __restrict__ bias, const float* __restrict__ gamma,
                               const float* __restrict__ beta, unsigned short* __restrict__ out,
                               int N) {
  __shared__ unsigned short As[128 * 32];  // [row][k] 64 B/row
  __shared__ unsigned short Ws[128 * 32];  // [n][k]   64 B/row
  int tid = threadIdx.x;
  int lane = tid & 63;
  int wv = tid >> 6;
  int q = lane >> 4;
  int c0 = lane & 15;
  int row0 = blockIdx.x * 128;

  f32x4 acc[2][8];
#pragma unroll
  for (int mt = 0; mt < 2; ++mt)
#pragma unroll
    for (int nt = 0; nt < 8; ++nt) acc[mt][nt] = (f32x4){0.f, 0.f, 0.f, 0.f};

#pragma unroll
  for (int ks = 0; ks < 8; ++ks) {
    int kk = ks * 32;
    const unsigned short* Asrc = (kk < 128) ? agg : feat;
    int kcol = kk & 127;
    __syncthreads();
#pragma unroll
    for (int i = 0; i < 2; ++i) {
      int c = tid + i * 256;
      int r = c >> 2, part = c & 3;
      int gr = row0 + r;
      int4 v = {0, 0, 0, 0};
      if (gr < N) v = *(const int4*)(Asrc + (size_t)gr * kC + kcol + part * 8);
      *(int4*)&As[r * 32 + part * 8] = v;
    }
#pragma unroll
    for (int i = 0; i < 2; ++i) {
      int c = tid + i * 256;
      int r = c >> 2, part = c & 3;
      int4 v = *(const int4*)(wcat + r * 256 + kk + part * 8);
      *(int4*)&Ws[r * 32 + part * 8] = v;
    }
    __syncthreads();

    bf16x8 a0 = *(const bf16x8*)&As[(wv * 32 + c0) * 32 + q * 8];
    bf16x8 a1 = *(const bf16x8*)&As[(wv * 32 + 16 + c0) * 32 + q * 8];
#pragma unroll
    for (int nt = 0; nt < 8; ++nt) {
      bf16x8 b = *(const bf16x8*)&Ws[(nt * 16 + c0) * 32 + q * 8];
      acc[0][nt] = __builtin_amdgcn_mfma_f32_16x16x32_bf16(a0, b, acc[0][nt], 0, 0, 0);
      acc[1][nt] = __builtin_amdgcn_mfma_f32_16x16x32_bf16(a1, b, acc[1][nt], 0, 0, 0);
    }
  }

  float bcol[8], gcol[8], ecol[8];
#pragma unroll
  for (int nt = 0; nt < 8; ++nt) {
    bcol[nt] = bias[nt * 16 + c0];
    gcol[nt] = gamma[nt * 16 + c0];
    ecol[nt] = beta[nt * 16 + c0];
  }
  int rbase = row0 + wv * 32;
#pragma unroll
  for (int mt = 0; mt < 2; ++mt) {
#pragma unroll
    for (int reg = 0; reg < 4; ++reg) {
      int row = rbase + mt * 16 + q * 4 + reg;
      float v[8];
      float s1 = 0.f, s2 = 0.f;
#pragma unroll
      for (int nt = 0; nt < 8; ++nt) {
        float t = acc[mt][nt][reg] + bcol[nt];
        v[nt] = t;
        s1 += t;
        s2 += t * t;
      }
#pragma unroll
      for (int m = 1; m < 16; m <<= 1) {
        s1 += __shfl_xor(s1, m, 64);
        s2 += __shfl_xor(s2, m, 64);
      }
      float mu = s1 * (1.f / 128.f);
      float var = s2 * (1.f / 128.f) - mu * mu;
      float rs = rsqrtf(var + 1e-5f);
      if (row < N) {
#pragma unroll
        for (int nt = 0; nt < 8; ++nt) {
          float o = fmaxf((v[nt] - mu) * rs * gcol[nt] + ecol[nt], 0.f);
          unsigned short h = f2bf(o);
          unsigned up = __shfl_xor((unsigned)h, 1, 64);
          if ((lane & 1) == 0) {
            *(unsigned*)(out + (size_t)row * kC + nt * 16 + c0) = (unsigned)h | (up << 16);
          }
        }
      }
    }
  }
}

// ---- final head: out[r] = feat_u[r,:] . lin_w + lin_b ----
__global__ void head_kernel(const unsigned short* __restrict__ fu, const float* __restrict__ lw,
                            const float* __restrict__ lb, float* __restrict__ out) {
  int w = (blockIdx.x * blockDim.x + threadIdx.x) >> 6;
  int lane = threadIdx.x & 63;
  if (w >= kB) return;
  unsigned v = *(const unsigned*)(fu + w * kC + lane * 2);
  float2 ww = *(const float2*)(lw + lane * 2);
  float p = __uint_as_float(v << 16) * ww.x + __uint_as_float(v & 0xffff0000u) * ww.y;
#pragma unroll
  for (int m = 1; m < 64; m <<= 1) p += __shfl_xor(p, m, 64);
  if (lane == 0) out[w] = p + lb[0];
}

extern "C" void kernel_launch(void* const* d_in, const int* in_sizes, int n_in,
                              void* d_out, int out_size, void* d_ws, size_t ws_size,
                              hipStream_t stream) {
  const float* x_user = (const float*)d_in[0];
  const float* x_item = (const float*)d_in[1];
  const int* e_ui_src = (const int*)d_in[2];
  const int* e_ui_dst = (const int*)d_in[3];
  const int* e_iu_src = (const int*)d_in[4];
  const int* e_iu_dst = (const int*)d_in[5];
  const float* w_rel  = (const float*)d_in[6];
  const float* w_root = (const float*)d_in[7];
  const float* bvec   = (const float*)d_in[8];
  const float* ln_g   = (const float*)d_in[9];
  const float* ln_b   = (const float*)d_in[10];
  const float* lin_w  = (const float*)d_in[11];
  const float* lin_b  = (const float*)d_in[12];

  char* p = (char*)d_ws;
  auto carve = [&](size_t bytes) -> char* {
    char* r = p;
    p += (bytes + 255) & ~size_t(255);
    return r;
  };
  unsigned short* fu[2] = {(unsigned short*)carve((size_t)kNU * kC * 2),
                           (unsigned short*)carve((size_t)kNU * kC * 2)};
  unsigned short* fi[2] = {(unsigned short*)carve((size_t)kNI * kC * 2),
                           (unsigned short*)carve((size_t)kNI * kC * 2)};
  unsigned short* agg  = (unsigned short*)carve((size_t)kNU * kC * 2);
  unsigned short* wcat = (unsigned short*)carve((size_t)4 * 128 * 256 * 2);
  int* bh_i   = (int*)carve((size_t)kNBK * 256 * 4);
  int* bo_i   = (int*)carve((size_t)kNBK * 256 * 4);
  int* bh_u   = (int*)carve((size_t)kNBK * 256 * 4);
  int* bo_u   = (int*)carve((size_t)kNBK * 256 * 4);
  int* base_i = (int*)carve(257 * 4);
  int* base_u = (int*)carve(257 * 4);
  unsigned* packed_i = (unsigned*)carve((size_t)kE * 4);
  unsigned* packed_u = (unsigned*)carve((size_t)kE * 4);
  int* col_i    = (int*)carve((size_t)kE * 4);
  int* col_u    = (int*)carve((size_t)kE * 4);
  int* rowptr_i = (int*)carve((size_t)(kNI + 1) * 4);
  int* rowptr_u = (int*)carve((size_t)(kNU + 1) * 4);

  int cvtN = (kNU * kC + kNI * kC) / 4;
  cvt_kernel<<<(cvtN + 255) / 256, 256, 0, stream>>>(x_user, x_item, fu[0], fi[0]);
  prep_w_kernel<<<512, 256, 0, stream>>>(w_rel, w_root, wcat);

  // CSR build, item-dst (shift 8: 196 buckets of 256) and user-dst (shift 9: 196 of 512)
  binA_kernel<<<kNBK, 256, 0, stream>>>(e_ui_dst, 8, bh_i);
  binA_kernel<<<kNBK, 256, 0, stream>>>(e_iu_dst, 9, bh_u);
  binB_kernel<<<1, 256, 0, stream>>>(bh_i, bo_i, base_i);
  binB_kernel<<<1, 256, 0, stream>>>(bh_u, bo_u, base_u);
  binC_kernel<<<kNBK, 256, 0, stream>>>(e_ui_src, e_ui_dst, 8, bo_i, base_i, packed_i);
  binC_kernel<<<kNBK, 256, 0, stream>>>(e_iu_src, e_iu_dst, 9, bo_u, base_u, packed_u);
  binD_kernel<<<196, 256, 0, stream>>>(packed_i, base_i, 256, kNI, col_i, rowptr_i);
  binD_kernel<<<196, 256, 0, stream>>>(packed_u, base_u, 512, kNU, col_u, rowptr_u);

  int cur = 0;
  for (int l = 0; l < 2; ++l) {
    pull_kernel<<<(kNI + 3) / 4, 256, 0, stream>>>(rowptr_i, col_i, fu[cur], agg, kNI);
    gemm_ln_kernel<<<(kNI + 127) / 128, 256, 0, stream>>>(
        agg, fi[cur], wcat + (size_t)(l * 2 + 0) * 128 * 256,
        bvec + (size_t)(l * 2 + 0) * kC, ln_g + (size_t)(l * 2 + 1) * kC,
        ln_b + (size_t)(l * 2 + 1) * kC, fi[1 - cur], kNI);
    pull_kernel<<<(kNU + 3) / 4, 256, 0, stream>>>(rowptr_u, col_u, fi[cur], agg, kNU);
    gemm_ln_kernel<<<(kNU + 127) / 128, 256, 0, stream>>>(
        agg, fu[cur], wcat + (size_t)(l * 2 + 1) * 128 * 256,
        bvec + (size_t)(l * 2 + 1) * kC, ln_g + (size_t)(l * 2 + 0) * kC,
        ln_b + (size_t)(l * 2 + 0) * kC, fu[1 - cur], kNU);
    cur ^= 1;
  }

  head_kernel<<<(kB + 3) / 4, 256, 0, stream>>>(fu[cur], lin_w, lin_b, (float*)d_out);
}

// Round 4
// 456.095 us; speedup vs baseline: 1.8092x; 1.0429x over previous
//
#include <hip/hip_runtime.h>
#include <stdint.h>

static constexpr int kNU = 100000;
static constexpr int kNI = 50000;
static constexpr int kE  = 500000;
static constexpr int kC  = 128;
static constexpr int kB  = 1024;
static constexpr int kNBK = 256;  // binning blocks per direction
static constexpr int kCap = 4096; // max edges per coarse bucket (mean 2560)

typedef __attribute__((ext_vector_type(8))) short bf16x8;
typedef __attribute__((ext_vector_type(4))) float f32x4;

__device__ __forceinline__ unsigned short f2bf(float f) {
  unsigned u = __float_as_uint(f);
  unsigned r = (u + 0x7fffu + ((u >> 16) & 1u)) >> 16;
  return (unsigned short)r;
}

__device__ __forceinline__ void load_lds_16B(const void* gptr, void* lptr) {
  __builtin_amdgcn_global_load_lds(
      (const __attribute__((address_space(1))) unsigned*)gptr,
      (__attribute__((address_space(3))) unsigned*)lptr, 16, 0, 0);
}

// ---- fp32 -> bf16 feature conversion (both tables in one launch) ----
__global__ void cvt_kernel(const float* __restrict__ xu, const float* __restrict__ xi,
                           unsigned short* __restrict__ fu, unsigned short* __restrict__ fi) {
  int i = blockIdx.x * blockDim.x + threadIdx.x;  // float4 index
  const int nu4 = kNU * kC / 4;
  const int ni4 = kNI * kC / 4;
  if (i < nu4) {
    float4 v = ((const float4*)xu)[i];
    ushort4 o; o.x = f2bf(v.x); o.y = f2bf(v.y); o.z = f2bf(v.z); o.w = f2bf(v.w);
    ((ushort4*)fu)[i] = o;
  } else if (i < nu4 + ni4) {
    int j = i - nu4;
    float4 v = ((const float4*)xi)[j];
    ushort4 o; o.x = f2bf(v.x); o.y = f2bf(v.y); o.z = f2bf(v.z); o.w = f2bf(v.w);
    ((ushort4*)fi)[j] = o;
  }
}

// ---- weight prep: wcat[m][n][k] bf16, m = l*2+t; k<128 -> w_rel^T, k>=128 -> w_root^T ----
__global__ void prep_w_kernel(const float* __restrict__ wrel, const float* __restrict__ wroot,
                              unsigned short* __restrict__ wcat) {
  int id = blockIdx.x * 256 + threadIdx.x;  // 4*128*256 = 131072
  int m = id >> 15;
  int n = (id >> 8) & 127;
  int k = id & 255;
  float v = (k < 128) ? wrel[(m * 128 + k) * 128 + n] : wroot[(m * 128 + (k - 128)) * 128 + n];
  wcat[id] = f2bf(v);
}

// ================= LDS-binned CSR build (no global atomics), both dirs =================
__global__ void binA_kernel(const int* __restrict__ dst_i, const int* __restrict__ dst_u,
                            int* __restrict__ bh_i, int* __restrict__ bh_u) {
  __shared__ int h[256];
  int b = blockIdx.x;
  const int* dst;
  int shift;
  int* bh;
  int blk;
  if (b < kNBK) { dst = dst_i; shift = 8; bh = bh_i; blk = b; }
  else          { dst = dst_u; shift = 9; bh = bh_u; blk = b - kNBK; }
  int tid = threadIdx.x;
  h[tid] = 0;
  __syncthreads();
  int chunk = (kE + kNBK - 1) / kNBK;
  int beg = blk * chunk;
  int end = min(kE, beg + chunk);
  for (int i = beg + tid; i < end; i += 256) atomicAdd(&h[dst[i] >> shift], 1);
  __syncthreads();
  bh[blk * 256 + tid] = h[tid];
}

__global__ void binB_kernel(const int* __restrict__ bh_i, int* __restrict__ bo_i,
                            int* __restrict__ base_i, const int* __restrict__ bh_u,
                            int* __restrict__ bo_u, int* __restrict__ base_u) {
  __shared__ int s[256];
  const int* bh;
  int* bo;
  int* base;
  if (blockIdx.x == 0) { bh = bh_i; bo = bo_i; base = base_i; }
  else                 { bh = bh_u; bo = bo_u; base = base_u; }
  int t = threadIdx.x;
  int run = 0;
  for (int b = 0; b < kNBK; ++b) {
    int v = bh[b * 256 + t];
    bo[b * 256 + t] = run;
    run += v;
  }
  s[t] = run;
  __syncthreads();
  for (int m = 1; m < 256; m <<= 1) {
    int tv = 0;
    if (t >= m) tv = s[t - m];
    __syncthreads();
    s[t] += tv;
    __syncthreads();
  }
  base[t] = s[t] - run;
  if (t == 255) base[256] = s[255];
}

__global__ void binC_kernel(const int* __restrict__ src_i, const int* __restrict__ dst_i,
                            const int* __restrict__ bo_i, const int* __restrict__ base_i,
                            unsigned* __restrict__ packed_i, const int* __restrict__ src_u,
                            const int* __restrict__ dst_u, const int* __restrict__ bo_u,
                            const int* __restrict__ base_u, unsigned* __restrict__ packed_u) {
  __shared__ int cur[256];
  int b = blockIdx.x;
  const int *src, *dst, *bo, *base;
  unsigned* packed;
  int shift, blk;
  if (b < kNBK) { src = src_i; dst = dst_i; bo = bo_i; base = base_i; packed = packed_i; shift = 8; blk = b; }
  else          { src = src_u; dst = dst_u; bo = bo_u; base = base_u; packed = packed_u; shift = 9; blk = b - kNBK; }
  int tid = threadIdx.x;
  cur[tid] = base[tid] + bo[blk * 256 + tid];
  __syncthreads();
  int chunk = (kE + kNBK - 1) / kNBK;
  int beg = blk * chunk;
  int end = min(kE, beg + chunk);
  int mask = (1 << shift) - 1;
  for (int i = beg + tid; i < end; i += 256) {
    int d = dst[i];
    int p = atomicAdd(&cur[d >> shift], 1);
    packed[p] = (unsigned)src[i] | ((unsigned)(d & mask) << 17);
  }
}

__launch_bounds__(256)
__global__ void binD_kernel(const unsigned* __restrict__ packed_i, const int* __restrict__ base_i,
                            int* __restrict__ col_i, int* __restrict__ rowptr_i,
                            const unsigned* __restrict__ packed_u, const int* __restrict__ base_u,
                            int* __restrict__ col_u, int* __restrict__ rowptr_u) {
  __shared__ unsigned ent[kCap];
  __shared__ int srt[kCap];
  __shared__ int hist[512];
  __shared__ int cur[512];
  int b = blockIdx.x;
  const unsigned* packed;
  const int* base;
  int* col;
  int* rowptr;
  int bsize, Nd, bb;
  if (b < 196) { packed = packed_i; base = base_i; col = col_i; rowptr = rowptr_i; bsize = 256; Nd = kNI; bb = b; }
  else         { packed = packed_u; base = base_u; col = col_u; rowptr = rowptr_u; bsize = 512; Nd = kNU; bb = b - 196; }
  int tid = threadIdx.x;
  int seg_beg = base[bb], seg_end = base[bb + 1];
  int cnt = seg_end - seg_beg;
  if (cnt > kCap) cnt = kCap;
  hist[tid] = 0;
  hist[tid + 256] = 0;
  __syncthreads();
  for (int i = tid; i < cnt; i += 256) {
    unsigned e = packed[seg_beg + i];
    ent[i] = e;
    atomicAdd(&hist[e >> 17], 1);
  }
  __syncthreads();
  for (int d = 1; d < 512; d <<= 1) {
    int idx = (tid + 1) * 2 * d - 1;
    if (idx < 512) hist[idx] += hist[idx - d];
    __syncthreads();
  }
  if (tid == 0) hist[511] = 0;
  __syncthreads();
  for (int d = 256; d >= 1; d >>= 1) {
    int idx = (tid + 1) * 2 * d - 1;
    if (idx < 512) {
      int tmp = hist[idx - d];
      hist[idx - d] = hist[idx];
      hist[idx] += tmp;
    }
    __syncthreads();
  }
  for (int j = tid; j < bsize; j += 256) {
    int n = bb * bsize + j;
    if (n < Nd) rowptr[n] = seg_beg + hist[j];
  }
  if (bb == 195 && tid == 0) rowptr[Nd] = seg_end;
  cur[tid] = hist[tid];
  cur[tid + 256] = hist[tid + 256];
  __syncthreads();
  for (int i = tid; i < cnt; i += 256) {
    unsigned e = ent[i];
    int p = atomicAdd(&cur[e >> 17], 1);
    srt[p] = (int)(e & 0x1FFFFu);
  }
  __syncthreads();
  for (int i = tid; i < cnt; i += 256) col[seg_beg + i] = srt[i];
}

// ---- pull aggregation, both dirs in one launch: 4 rows per wave, 8-deep MLP ----
__global__ void pull2_kernel(const int* __restrict__ rp_i, const int* __restrict__ col_i,
                             const unsigned short* __restrict__ ft_i, unsigned short* __restrict__ ag_i,
                             const int* __restrict__ rp_u, const int* __restrict__ col_u,
                             const unsigned short* __restrict__ ft_u, unsigned short* __restrict__ ag_u,
                             int nbi) {
  int b = blockIdx.x;
  const int *rowptr, *col;
  const unsigned short* feat;
  unsigned short* agg;
  int Nd, base;
  if (b < nbi) { rowptr = rp_i; col = col_i; feat = ft_i; agg = ag_i; Nd = kNI; base = b * 16; }
  else         { rowptr = rp_u; col = col_u; feat = ft_u; agg = ag_u; Nd = kNU; base = (b - nbi) * 16; }
  int wv = threadIdx.x >> 6;
  int lane = threadIdx.x & 63;
  int r0 = base + wv * 4;
  int beg[4], end[4];
#pragma unroll
  for (int t = 0; t < 4; ++t) {
    int r = r0 + t;
    beg[t] = (r < Nd) ? rowptr[r] : 0;
    end[t] = (r < Nd) ? rowptr[r + 1] : 0;
  }
  float a0[4] = {0.f, 0.f, 0.f, 0.f}, a1[4] = {0.f, 0.f, 0.f, 0.f};
  float b0[4] = {0.f, 0.f, 0.f, 0.f}, b1[4] = {0.f, 0.f, 0.f, 0.f};
  int off = lane * 2;
  int maxit = end[0] - beg[0];
#pragma unroll
  for (int t = 1; t < 4; ++t) {
    int len = end[t] - beg[t];
    maxit = (len > maxit) ? len : maxit;
  }
  for (int j = 0; j < maxit; j += 2) {
#pragma unroll
    for (int t = 0; t < 4; ++t) {
      int p = beg[t] + j;
      if (p < end[t]) {
        unsigned v = *(const unsigned*)(feat + (size_t)col[p] * kC + off);
        a0[t] += __uint_as_float(v << 16);
        a1[t] += __uint_as_float(v & 0xffff0000u);
      }
      if (p + 1 < end[t]) {
        unsigned v = *(const unsigned*)(feat + (size_t)col[p + 1] * kC + off);
        b0[t] += __uint_as_float(v << 16);
        b1[t] += __uint_as_float(v & 0xffff0000u);
      }
    }
  }
#pragma unroll
  for (int t = 0; t < 4; ++t) {
    int r = r0 + t;
    if (r < Nd) {
      unsigned rw = (unsigned)f2bf(a0[t] + b0[t]) | ((unsigned)f2bf(a1[t] + b1[t]) << 16);
      ((unsigned*)agg)[(size_t)r * 64 + lane] = rw;
    }
  }
}

// ---- MFMA GEMM both dirs: out = LN([agg|feat] @ wcat^T(+bias)) relu -> bf16 ----
// block: 128 rows x 128 cols, 4 waves; global_load_lds 16B staging
__launch_bounds__(256)
__global__ void gemm2_kernel(int nbi,
                             const unsigned short* __restrict__ ag_i, const unsigned short* __restrict__ ft_i,
                             const unsigned short* __restrict__ wc_i, const float* __restrict__ bs_i,
                             const float* __restrict__ gm_i, const float* __restrict__ bt_i,
                             unsigned short* __restrict__ out_i,
                             const unsigned short* __restrict__ ag_u, const unsigned short* __restrict__ ft_u,
                             const unsigned short* __restrict__ wc_u, const float* __restrict__ bs_u,
                             const float* __restrict__ gm_u, const float* __restrict__ bt_u,
                             unsigned short* __restrict__ out_u) {
  __shared__ unsigned short As[128 * 32];  // [row][k] 64 B/row
  __shared__ unsigned short Ws[128 * 32];  // [n][k]   64 B/row
  int b = blockIdx.x;
  const unsigned short *agg, *feat, *wcat;
  const float *bias, *gamma, *beta;
  unsigned short* out;
  int N, row0;
  if (b < nbi) {
    agg = ag_i; feat = ft_i; wcat = wc_i; bias = bs_i; gamma = gm_i; beta = bt_i; out = out_i;
    N = kNI; row0 = b * 128;
  } else {
    agg = ag_u; feat = ft_u; wcat = wc_u; bias = bs_u; gamma = gm_u; beta = bt_u; out = out_u;
    N = kNU; row0 = (b - nbi) * 128;
  }
  int tid = threadIdx.x;
  int lane = tid & 63;
  int wv = tid >> 6;
  int q = lane >> 4;
  int c0 = lane & 15;

  f32x4 acc[2][8];
#pragma unroll
  for (int mt = 0; mt < 2; ++mt)
#pragma unroll
    for (int nt = 0; nt < 8; ++nt) acc[mt][nt] = (f32x4){0.f, 0.f, 0.f, 0.f};

#pragma unroll
  for (int ks = 0; ks < 8; ++ks) {
    int kk = ks * 32;
    const unsigned short* Asrc = (ks < 4) ? agg : feat;
    int kcol = kk & 127;
    __syncthreads();
    // A: 512 16B chunks; chunk c -> row r=c>>2, part=c&3, LDS shorts [c*8, c*8+8)
#pragma unroll
    for (int i = 0; i < 2; ++i) {
      int c = tid + i * 256;
      int r = c >> 2, part = c & 3;
      // rows beyond N read in-workspace garbage; masked at store
      load_lds_16B(Asrc + (size_t)(row0 + r) * kC + kcol + part * 8, &As[(c & ~63) * 8]);
    }
#pragma unroll
    for (int i = 0; i < 2; ++i) {
      int c = tid + i * 256;
      int r = c >> 2, part = c & 3;
      load_lds_16B(wcat + r * 256 + kk + part * 8, &Ws[(c & ~63) * 8]);
    }
    __syncthreads();

    bf16x8 a0 = *(const bf16x8*)&As[(wv * 32 + c0) * 32 + q * 8];
    bf16x8 a1 = *(const bf16x8*)&As[(wv * 32 + 16 + c0) * 32 + q * 8];
#pragma unroll
    for (int nt = 0; nt < 8; ++nt) {
      bf16x8 bfr = *(const bf16x8*)&Ws[(nt * 16 + c0) * 32 + q * 8];
      acc[0][nt] = __builtin_amdgcn_mfma_f32_16x16x32_bf16(a0, bfr, acc[0][nt], 0, 0, 0);
      acc[1][nt] = __builtin_amdgcn_mfma_f32_16x16x32_bf16(a1, bfr, acc[1][nt], 0, 0, 0);
    }
  }

  float bcol[8], gcol[8], ecol[8];
#pragma unroll
  for (int nt = 0; nt < 8; ++nt) {
    bcol[nt] = bias[nt * 16 + c0];
    gcol[nt] = gamma[nt * 16 + c0];
    ecol[nt] = beta[nt * 16 + c0];
  }
  int rbase = row0 + wv * 32;
#pragma unroll
  for (int mt = 0; mt < 2; ++mt) {
#pragma unroll
    for (int reg = 0; reg < 4; ++reg) {
      int row = rbase + mt * 16 + q * 4 + reg;
      float v[8];
      float s1 = 0.f, s2 = 0.f;
#pragma unroll
      for (int nt = 0; nt < 8; ++nt) {
        float t = acc[mt][nt][reg] + bcol[nt];
        v[nt] = t;
        s1 += t;
        s2 += t * t;
      }
#pragma unroll
      for (int m = 1; m < 16; m <<= 1) {
        s1 += __shfl_xor(s1, m, 64);
        s2 += __shfl_xor(s2, m, 64);
      }
      float mu = s1 * (1.f / 128.f);
      float var = s2 * (1.f / 128.f) - mu * mu;
      float rs = rsqrtf(var + 1e-5f);
      if (row < N) {
#pragma unroll
        for (int nt = 0; nt < 8; ++nt) {
          float o = fmaxf((v[nt] - mu) * rs * gcol[nt] + ecol[nt], 0.f);
          unsigned short h = f2bf(o);
          unsigned up = __shfl_xor((unsigned)h, 1, 64);
          if ((lane & 1) == 0) {
            *(unsigned*)(out + (size_t)row * kC + nt * 16 + c0) = (unsigned)h | (up << 16);
          }
        }
      }
    }
  }
}

// ---- final head: out[r] = feat_u[r,:] . lin_w + lin_b ----
__global__ void head_kernel(const unsigned short* __restrict__ fu, const float* __restrict__ lw,
                            const float* __restrict__ lb, float* __restrict__ out) {
  int w = (blockIdx.x * blockDim.x + threadIdx.x) >> 6;
  int lane = threadIdx.x & 63;
  if (w >= kB) return;
  unsigned v = *(const unsigned*)(fu + w * kC + lane * 2);
  float2 ww = *(const float2*)(lw + lane * 2);
  float p = __uint_as_float(v << 16) * ww.x + __uint_as_float(v & 0xffff0000u) * ww.y;
#pragma unroll
  for (int m = 1; m < 64; m <<= 1) p += __shfl_xor(p, m, 64);
  if (lane == 0) out[w] = p + lb[0];
}

extern "C" void kernel_launch(void* const* d_in, const int* in_sizes, int n_in,
                              void* d_out, int out_size, void* d_ws, size_t ws_size,
                              hipStream_t stream) {
  const float* x_user = (const float*)d_in[0];
  const float* x_item = (const float*)d_in[1];
  const int* e_ui_src = (const int*)d_in[2];
  const int* e_ui_dst = (const int*)d_in[3];
  const int* e_iu_src = (const int*)d_in[4];
  const int* e_iu_dst = (const int*)d_in[5];
  const float* w_rel  = (const float*)d_in[6];
  const float* w_root = (const float*)d_in[7];
  const float* bvec   = (const float*)d_in[8];
  const float* ln_g   = (const float*)d_in[9];
  const float* ln_b   = (const float*)d_in[10];
  const float* lin_w  = (const float*)d_in[11];
  const float* lin_b  = (const float*)d_in[12];

  char* p = (char*)d_ws;
  auto carve = [&](size_t bytes) -> char* {
    char* r = p;
    p += (bytes + 255) & ~size_t(255);
    return r;
  };
  unsigned short* fu[2] = {(unsigned short*)carve((size_t)kNU * kC * 2),
                           (unsigned short*)carve((size_t)kNU * kC * 2)};
  unsigned short* fi[2] = {(unsigned short*)carve((size_t)kNI * kC * 2),
                           (unsigned short*)carve((size_t)kNI * kC * 2)};
  unsigned short* agg_i = (unsigned short*)carve((size_t)kNI * kC * 2);
  unsigned short* agg_u = (unsigned short*)carve((size_t)kNU * kC * 2);
  unsigned short* wcat  = (unsigned short*)carve((size_t)4 * 128 * 256 * 2);
  int* bh_i   = (int*)carve((size_t)kNBK * 256 * 4);
  int* bo_i   = (int*)carve((size_t)kNBK * 256 * 4);
  int* bh_u   = (int*)carve((size_t)kNBK * 256 * 4);
  int* bo_u   = (int*)carve((size_t)kNBK * 256 * 4);
  int* base_i = (int*)carve(257 * 4);
  int* base_u = (int*)carve(257 * 4);
  unsigned* packed_i = (unsigned*)carve((size_t)kE * 4);
  unsigned* packed_u = (unsigned*)carve((size_t)kE * 4);
  int* col_i    = (int*)carve((size_t)kE * 4);
  int* col_u    = (int*)carve((size_t)kE * 4);
  int* rowptr_i = (int*)carve((size_t)(kNI + 1) * 4);
  int* rowptr_u = (int*)carve((size_t)(kNU + 1) * 4);

  int cvtN = (kNU * kC + kNI * kC) / 4;
  cvt_kernel<<<(cvtN + 255) / 256, 256, 0, stream>>>(x_user, x_item, fu[0], fi[0]);
  prep_w_kernel<<<512, 256, 0, stream>>>(w_rel, w_root, wcat);

  binA_kernel<<<2 * kNBK, 256, 0, stream>>>(e_ui_dst, e_iu_dst, bh_i, bh_u);
  binB_kernel<<<2, 256, 0, stream>>>(bh_i, bo_i, base_i, bh_u, bo_u, base_u);
  binC_kernel<<<2 * kNBK, 256, 0, stream>>>(e_ui_src, e_ui_dst, bo_i, base_i, packed_i,
                                            e_iu_src, e_iu_dst, bo_u, base_u, packed_u);
  binD_kernel<<<392, 256, 0, stream>>>(packed_i, base_i, col_i, rowptr_i,
                                       packed_u, base_u, col_u, rowptr_u);

  int nbi_p = (kNI + 15) / 16;       // 3125
  int nbu_p = (kNU + 15) / 16;       // 6250
  int nbi_g = (kNI + 127) / 128;     // 391
  int nbu_g = (kNU + 127) / 128;     // 782

  int cur = 0;
  for (int l = 0; l < 2; ++l) {
    pull2_kernel<<<nbi_p + nbu_p, 256, 0, stream>>>(rowptr_i, col_i, fu[cur], agg_i,
                                                    rowptr_u, col_u, fi[cur], agg_u, nbi_p);
    gemm2_kernel<<<nbi_g + nbu_g, 256, 0, stream>>>(
        nbi_g,
        agg_i, fi[cur], wcat + (size_t)(l * 2 + 0) * 128 * 256,
        bvec + (size_t)(l * 2 + 0) * kC, ln_g + (size_t)(l * 2 + 1) * kC,
        ln_b + (size_t)(l * 2 + 1) * kC, fi[1 - cur],
        agg_u, fu[cur], wcat + (size_t)(l * 2 + 1) * 128 * 256,
        bvec + (size_t)(l * 2 + 1) * kC, ln_g + (size_t)(l * 2 + 0) * kC,
        ln_b + (size_t)(l * 2 + 0) * kC, fu[1 - cur]);
    cur ^= 1;
  }

  head_kernel<<<(kB + 3) / 4, 256, 0, stream>>>(fu[cur], lin_w, lin_b, (float*)d_out);
}

// Round 5
// 337.112 us; speedup vs baseline: 2.4477x; 1.3529x over previous
//
#include <hip/hip_runtime.h>
#include <stdint.h>

static constexpr int kNU = 100000;
static constexpr int kNI = 50000;
static constexpr int kE  = 500000;
static constexpr int kC  = 128;
static constexpr int kB  = 1024;
static constexpr int kNBK = 256;  // binning blocks per direction
static constexpr int kCap = 4096; // max edges per coarse bucket (mean 2560)

typedef __attribute__((ext_vector_type(8))) short bf16x8;
typedef __attribute__((ext_vector_type(4))) float f32x4;

__device__ __forceinline__ unsigned short f2bf(float f) {
  unsigned u = __float_as_uint(f);
  unsigned r = (u + 0x7fffu + ((u >> 16) & 1u)) >> 16;
  return (unsigned short)r;
}

__device__ __forceinline__ void load_lds_16B(const void* gptr, void* lptr) {
  __builtin_amdgcn_global_load_lds(
      (const __attribute__((address_space(1))) unsigned*)gptr,
      (__attribute__((address_space(3))) unsigned*)lptr, 16, 0, 0);
}

// ---- fp32 -> bf16 feature conversion (both tables in one launch) ----
__global__ void cvt_kernel(const float* __restrict__ xu, const float* __restrict__ xi,
                           unsigned short* __restrict__ fu, unsigned short* __restrict__ fi) {
  int i = blockIdx.x * blockDim.x + threadIdx.x;  // float4 index
  const int nu4 = kNU * kC / 4;
  const int ni4 = kNI * kC / 4;
  if (i < nu4) {
    float4 v = ((const float4*)xu)[i];
    ushort4 o; o.x = f2bf(v.x); o.y = f2bf(v.y); o.z = f2bf(v.z); o.w = f2bf(v.w);
    ((ushort4*)fu)[i] = o;
  } else if (i < nu4 + ni4) {
    int j = i - nu4;
    float4 v = ((const float4*)xi)[j];
    ushort4 o; o.x = f2bf(v.x); o.y = f2bf(v.y); o.z = f2bf(v.z); o.w = f2bf(v.w);
    ((ushort4*)fi)[j] = o;
  }
}

// ---- weight prep: wcat[m][n][k] bf16, m = l*2+t; k<128 -> w_rel^T, k>=128 -> w_root^T ----
__global__ void prep_w_kernel(const float* __restrict__ wrel, const float* __restrict__ wroot,
                              unsigned short* __restrict__ wcat) {
  int id = blockIdx.x * 256 + threadIdx.x;  // 4*128*256 = 131072
  int m = id >> 15;
  int n = (id >> 8) & 127;
  int k = id & 255;
  float v = (k < 128) ? wrel[(m * 128 + k) * 128 + n] : wroot[(m * 128 + (k - 128)) * 128 + n];
  wcat[id] = f2bf(v);
}

// ================= LDS-binned CSR build (no global atomics), both dirs =================
__global__ void binA_kernel(const int* __restrict__ dst_i, const int* __restrict__ dst_u,
                            int* __restrict__ bh_i, int* __restrict__ bh_u) {
  __shared__ int h[256];
  int b = blockIdx.x;
  const int* dst;
  int shift;
  int* bh;
  int blk;
  if (b < kNBK) { dst = dst_i; shift = 8; bh = bh_i; blk = b; }
  else          { dst = dst_u; shift = 9; bh = bh_u; blk = b - kNBK; }
  int tid = threadIdx.x;
  h[tid] = 0;
  __syncthreads();
  int chunk = (kE + kNBK - 1) / kNBK;
  int beg = blk * chunk;
  int end = min(kE, beg + chunk);
  for (int i = beg + tid; i < end; i += 256) atomicAdd(&h[dst[i] >> shift], 1);
  __syncthreads();
  bh[blk * 256 + tid] = h[tid];
}

__global__ void binB_kernel(const int* __restrict__ bh_i, int* __restrict__ bo_i,
                            int* __restrict__ base_i, const int* __restrict__ bh_u,
                            int* __restrict__ bo_u, int* __restrict__ base_u) {
  __shared__ int s[256];
  const int* bh;
  int* bo;
  int* base;
  if (blockIdx.x == 0) { bh = bh_i; bo = bo_i; base = base_i; }
  else                 { bh = bh_u; bo = bo_u; base = base_u; }
  int t = threadIdx.x;
  int run = 0;
  for (int b = 0; b < kNBK; ++b) {
    int v = bh[b * 256 + t];
    bo[b * 256 + t] = run;
    run += v;
  }
  s[t] = run;
  __syncthreads();
  for (int m = 1; m < 256; m <<= 1) {
    int tv = 0;
    if (t >= m) tv = s[t - m];
    __syncthreads();
    s[t] += tv;
    __syncthreads();
  }
  base[t] = s[t] - run;
  if (t == 255) base[256] = s[255];
}

__global__ void binC_kernel(const int* __restrict__ src_i, const int* __restrict__ dst_i,
                            const int* __restrict__ bo_i, const int* __restrict__ base_i,
                            unsigned* __restrict__ packed_i, const int* __restrict__ src_u,
                            const int* __restrict__ dst_u, const int* __restrict__ bo_u,
                            const int* __restrict__ base_u, unsigned* __restrict__ packed_u) {
  __shared__ int cur[256];
  int b = blockIdx.x;
  const int *src, *dst, *bo, *base;
  unsigned* packed;
  int shift, blk;
  if (b < kNBK) { src = src_i; dst = dst_i; bo = bo_i; base = base_i; packed = packed_i; shift = 8; blk = b; }
  else          { src = src_u; dst = dst_u; bo = bo_u; base = base_u; packed = packed_u; shift = 9; blk = b - kNBK; }
  int tid = threadIdx.x;
  cur[tid] = base[tid] + bo[blk * 256 + tid];
  __syncthreads();
  int chunk = (kE + kNBK - 1) / kNBK;
  int beg = blk * chunk;
  int end = min(kE, beg + chunk);
  int mask = (1 << shift) - 1;
  for (int i = beg + tid; i < end; i += 256) {
    int d = dst[i];
    int p = atomicAdd(&cur[d >> shift], 1);
    packed[p] = (unsigned)src[i] | ((unsigned)(d & mask) << 17);
  }
}

__launch_bounds__(256)
__global__ void binD_kernel(const unsigned* __restrict__ packed_i, const int* __restrict__ base_i,
                            int* __restrict__ col_i, int* __restrict__ rowptr_i,
                            const unsigned* __restrict__ packed_u, const int* __restrict__ base_u,
                            int* __restrict__ col_u, int* __restrict__ rowptr_u) {
  __shared__ unsigned ent[kCap];
  __shared__ int srt[kCap];
  __shared__ int hist[512];
  __shared__ int cur[512];
  int b = blockIdx.x;
  const unsigned* packed;
  const int* base;
  int* col;
  int* rowptr;
  int bsize, Nd, bb;
  if (b < 196) { packed = packed_i; base = base_i; col = col_i; rowptr = rowptr_i; bsize = 256; Nd = kNI; bb = b; }
  else         { packed = packed_u; base = base_u; col = col_u; rowptr = rowptr_u; bsize = 512; Nd = kNU; bb = b - 196; }
  int tid = threadIdx.x;
  int seg_beg = base[bb], seg_end = base[bb + 1];
  int cnt = seg_end - seg_beg;
  if (cnt > kCap) cnt = kCap;
  hist[tid] = 0;
  hist[tid + 256] = 0;
  __syncthreads();
  for (int i = tid; i < cnt; i += 256) {
    unsigned e = packed[seg_beg + i];
    ent[i] = e;
    atomicAdd(&hist[e >> 17], 1);
  }
  __syncthreads();
  for (int d = 1; d < 512; d <<= 1) {
    int idx = (tid + 1) * 2 * d - 1;
    if (idx < 512) hist[idx] += hist[idx - d];
    __syncthreads();
  }
  if (tid == 0) hist[511] = 0;
  __syncthreads();
  for (int d = 256; d >= 1; d >>= 1) {
    int idx = (tid + 1) * 2 * d - 1;
    if (idx < 512) {
      int tmp = hist[idx - d];
      hist[idx - d] = hist[idx];
      hist[idx] += tmp;
    }
    __syncthreads();
  }
  for (int j = tid; j < bsize; j += 256) {
    int n = bb * bsize + j;
    if (n < Nd) rowptr[n] = seg_beg + hist[j];
  }
  if (bb == 195 && tid == 0) rowptr[Nd] = seg_end;
  cur[tid] = hist[tid];
  cur[tid + 256] = hist[tid + 256];
  __syncthreads();
  for (int i = tid; i < cnt; i += 256) {
    unsigned e = ent[i];
    int p = atomicAdd(&cur[e >> 17], 1);
    srt[p] = (int)(e & 0x1FFFFu);
  }
  __syncthreads();
  for (int i = tid; i < cnt; i += 256) col[seg_beg + i] = srt[i];
}

// ---- pull aggregation v3: quarter-wave per row, 16B/lane gathers, index prefetch ----
// Each 16-lane quarter owns one dst row; lane covers channels qoff*8..+8 (16 B).
// Per iteration: 4 independent 16 B gathers (4 edges) + prefetch of next 4 col indices.
__global__ void pull3_kernel(const int* __restrict__ rp_i, const int* __restrict__ col_i,
                             const unsigned short* __restrict__ ft_i, unsigned short* __restrict__ ag_i,
                             const int* __restrict__ rp_u, const int* __restrict__ col_u,
                             const unsigned short* __restrict__ ft_u, unsigned short* __restrict__ ag_u,
                             int nbi) {
  int b = blockIdx.x;
  const int *rowptr, *col;
  const unsigned short* feat;
  unsigned short* agg;
  int Nd, rbase;
  if (b < nbi) { rowptr = rp_i; col = col_i; feat = ft_i; agg = ag_i; Nd = kNI; rbase = b * 16; }
  else         { rowptr = rp_u; col = col_u; feat = ft_u; agg = ag_u; Nd = kNU; rbase = (b - nbi) * 16; }
  int tid = threadIdx.x;
  int wv = tid >> 6;
  int lane = tid & 63;
  int qrow = lane >> 4;
  int qoff = lane & 15;
  int r = rbase + wv * 4 + qrow;
  int beg = 0, end = 0;
  if (r < Nd) {
    beg = rowptr[r];
    end = rowptr[r + 1];
  }
  float acc[8];
#pragma unroll
  for (int c = 0; c < 8; ++c) acc[c] = 0.f;

  int i0 = 0, i1 = 0, i2 = 0, i3 = 0;
  if (beg < end) {  // col padded with 4 zero ints past kE -> over-reads safe
    i0 = col[beg];
    i1 = col[beg + 1];
    i2 = col[beg + 2];
    i3 = col[beg + 3];
  }
  int choff = qoff * 8;
  for (int j = beg; j < end; j += 4) {
    int rem = end - j;
    int n0 = i0, n1 = i1, n2 = i2, n3 = i3;
    if (j + 4 < end) {
      n0 = col[j + 4];
      n1 = col[j + 5];
      n2 = col[j + 6];
      n3 = col[j + 7];
    }
    uint4 g0 = *(const uint4*)(feat + (size_t)i0 * kC + choff);
    uint4 g1 = *(const uint4*)(feat + (size_t)i1 * kC + choff);
    uint4 g2 = *(const uint4*)(feat + (size_t)i2 * kC + choff);
    uint4 g3 = *(const uint4*)(feat + (size_t)i3 * kC + choff);
    if (rem < 2) { g1.x = 0; g1.y = 0; g1.z = 0; g1.w = 0; }
    if (rem < 3) { g2.x = 0; g2.y = 0; g2.z = 0; g2.w = 0; }
    if (rem < 4) { g3.x = 0; g3.y = 0; g3.z = 0; g3.w = 0; }
#define ACC8(g)                                          \
    acc[0] += __uint_as_float((g).x << 16);              \
    acc[1] += __uint_as_float((g).x & 0xffff0000u);      \
    acc[2] += __uint_as_float((g).y << 16);              \
    acc[3] += __uint_as_float((g).y & 0xffff0000u);      \
    acc[4] += __uint_as_float((g).z << 16);              \
    acc[5] += __uint_as_float((g).z & 0xffff0000u);      \
    acc[6] += __uint_as_float((g).w << 16);              \
    acc[7] += __uint_as_float((g).w & 0xffff0000u);
    ACC8(g0)
    ACC8(g1)
    ACC8(g2)
    ACC8(g3)
#undef ACC8
    i0 = n0; i1 = n1; i2 = n2; i3 = n3;
  }
  if (r < Nd) {
    uint4 o;
    o.x = (unsigned)f2bf(acc[0]) | ((unsigned)f2bf(acc[1]) << 16);
    o.y = (unsigned)f2bf(acc[2]) | ((unsigned)f2bf(acc[3]) << 16);
    o.z = (unsigned)f2bf(acc[4]) | ((unsigned)f2bf(acc[5]) << 16);
    o.w = (unsigned)f2bf(acc[6]) | ((unsigned)f2bf(acc[7]) << 16);
    *(uint4*)(agg + (size_t)r * kC + choff) = o;
  }
}

// ---- MFMA GEMM both dirs: out = LN([agg|feat] @ wcat^T(+bias)) relu -> bf16 ----
__launch_bounds__(256)
__global__ void gemm2_kernel(int nbi,
                             const unsigned short* __restrict__ ag_i, const unsigned short* __restrict__ ft_i,
                             const unsigned short* __restrict__ wc_i, const float* __restrict__ bs_i,
                             const float* __restrict__ gm_i, const float* __restrict__ bt_i,
                             unsigned short* __restrict__ out_i,
                             const unsigned short* __restrict__ ag_u, const unsigned short* __restrict__ ft_u,
                             const unsigned short* __restrict__ wc_u, const float* __restrict__ bs_u,
                             const float* __restrict__ gm_u, const float* __restrict__ bt_u,
                             unsigned short* __restrict__ out_u) {
  __shared__ unsigned short As[128 * 32];  // [row][k] 64 B/row
  __shared__ unsigned short Ws[128 * 32];  // [n][k]   64 B/row
  int b = blockIdx.x;
  const unsigned short *agg, *feat, *wcat;
  const float *bias, *gamma, *beta;
  unsigned short* out;
  int N, row0;
  if (b < nbi) {
    agg = ag_i; feat = ft_i; wcat = wc_i; bias = bs_i; gamma = gm_i; beta = bt_i; out = out_i;
    N = kNI; row0 = b * 128;
  } else {
    agg = ag_u; feat = ft_u; wcat = wc_u; bias = bs_u; gamma = gm_u; beta = bt_u; out = out_u;
    N = kNU; row0 = (b - nbi) * 128;
  }
  int tid = threadIdx.x;
  int lane = tid & 63;
  int wv = tid >> 6;
  int q = lane >> 4;
  int c0 = lane & 15;

  f32x4 acc[2][8];
#pragma unroll
  for (int mt = 0; mt < 2; ++mt)
#pragma unroll
    for (int nt = 0; nt < 8; ++nt) acc[mt][nt] = (f32x4){0.f, 0.f, 0.f, 0.f};

#pragma unroll
  for (int ks = 0; ks < 8; ++ks) {
    int kk = ks * 32;
    const unsigned short* Asrc = (ks < 4) ? agg : feat;
    int kcol = kk & 127;
    __syncthreads();
#pragma unroll
    for (int i = 0; i < 2; ++i) {
      int c = tid + i * 256;
      int r = c >> 2, part = c & 3;
      load_lds_16B(Asrc + (size_t)(row0 + r) * kC + kcol + part * 8, &As[(c & ~63) * 8]);
    }
#pragma unroll
    for (int i = 0; i < 2; ++i) {
      int c = tid + i * 256;
      int r = c >> 2, part = c & 3;
      load_lds_16B(wcat + r * 256 + kk + part * 8, &Ws[(c & ~63) * 8]);
    }
    __syncthreads();

    bf16x8 a0 = *(const bf16x8*)&As[(wv * 32 + c0) * 32 + q * 8];
    bf16x8 a1 = *(const bf16x8*)&As[(wv * 32 + 16 + c0) * 32 + q * 8];
#pragma unroll
    for (int nt = 0; nt < 8; ++nt) {
      bf16x8 bfr = *(const bf16x8*)&Ws[(nt * 16 + c0) * 32 + q * 8];
      acc[0][nt] = __builtin_amdgcn_mfma_f32_16x16x32_bf16(a0, bfr, acc[0][nt], 0, 0, 0);
      acc[1][nt] = __builtin_amdgcn_mfma_f32_16x16x32_bf16(a1, bfr, acc[1][nt], 0, 0, 0);
    }
  }

  float bcol[8], gcol[8], ecol[8];
#pragma unroll
  for (int nt = 0; nt < 8; ++nt) {
    bcol[nt] = bias[nt * 16 + c0];
    gcol[nt] = gamma[nt * 16 + c0];
    ecol[nt] = beta[nt * 16 + c0];
  }
  int rbase = row0 + wv * 32;
#pragma unroll
  for (int mt = 0; mt < 2; ++mt) {
#pragma unroll
    for (int reg = 0; reg < 4; ++reg) {
      int row = rbase + mt * 16 + q * 4 + reg;
      float v[8];
      float s1 = 0.f, s2 = 0.f;
#pragma unroll
      for (int nt = 0; nt < 8; ++nt) {
        float t = acc[mt][nt][reg] + bcol[nt];
        v[nt] = t;
        s1 += t;
        s2 += t * t;
      }
#pragma unroll
      for (int m = 1; m < 16; m <<= 1) {
        s1 += __shfl_xor(s1, m, 64);
        s2 += __shfl_xor(s2, m, 64);
      }
      float mu = s1 * (1.f / 128.f);
      float var = s2 * (1.f / 128.f) - mu * mu;
      float rs = rsqrtf(var + 1e-5f);
      if (row < N) {
#pragma unroll
        for (int nt = 0; nt < 8; ++nt) {
          float o = fmaxf((v[nt] - mu) * rs * gcol[nt] + ecol[nt], 0.f);
          unsigned short h = f2bf(o);
          unsigned up = __shfl_xor((unsigned)h, 1, 64);
          if ((lane & 1) == 0) {
            *(unsigned*)(out + (size_t)row * kC + nt * 16 + c0) = (unsigned)h | (up << 16);
          }
        }
      }
    }
  }
}

// ---- final head: out[r] = feat_u[r,:] . lin_w + lin_b ----
__global__ void head_kernel(const unsigned short* __restrict__ fu, const float* __restrict__ lw,
                            const float* __restrict__ lb, float* __restrict__ out) {
  int w = (blockIdx.x * blockDim.x + threadIdx.x) >> 6;
  int lane = threadIdx.x & 63;
  if (w >= kB) return;
  unsigned v = *(const unsigned*)(fu + w * kC + lane * 2);
  float2 ww = *(const float2*)(lw + lane * 2);
  float p = __uint_as_float(v << 16) * ww.x + __uint_as_float(v & 0xffff0000u) * ww.y;
#pragma unroll
  for (int m = 1; m < 64; m <<= 1) p += __shfl_xor(p, m, 64);
  if (lane == 0) out[w] = p + lb[0];
}

extern "C" void kernel_launch(void* const* d_in, const int* in_sizes, int n_in,
                              void* d_out, int out_size, void* d_ws, size_t ws_size,
                              hipStream_t stream) {
  const float* x_user = (const float*)d_in[0];
  const float* x_item = (const float*)d_in[1];
  const int* e_ui_src = (const int*)d_in[2];
  const int* e_ui_dst = (const int*)d_in[3];
  const int* e_iu_src = (const int*)d_in[4];
  const int* e_iu_dst = (const int*)d_in[5];
  const float* w_rel  = (const float*)d_in[6];
  const float* w_root = (const float*)d_in[7];
  const float* bvec   = (const float*)d_in[8];
  const float* ln_g   = (const float*)d_in[9];
  const float* ln_b   = (const float*)d_in[10];
  const float* lin_w  = (const float*)d_in[11];
  const float* lin_b  = (const float*)d_in[12];

  char* p = (char*)d_ws;
  auto carve = [&](size_t bytes) -> char* {
    char* r = p;
    p += (bytes + 255) & ~size_t(255);
    return r;
  };
  unsigned short* fu[2] = {(unsigned short*)carve((size_t)kNU * kC * 2),
                           (unsigned short*)carve((size_t)kNU * kC * 2)};
  unsigned short* fi[2] = {(unsigned short*)carve((size_t)kNI * kC * 2),
                           (unsigned short*)carve((size_t)kNI * kC * 2)};
  unsigned short* agg_i = (unsigned short*)carve((size_t)kNI * kC * 2);
  unsigned short* agg_u = (unsigned short*)carve((size_t)kNU * kC * 2);
  unsigned short* wcat  = (unsigned short*)carve((size_t)4 * 128 * 256 * 2);
  int* bh_i   = (int*)carve((size_t)kNBK * 256 * 4);
  int* bo_i   = (int*)carve((size_t)kNBK * 256 * 4);
  int* bh_u   = (int*)carve((size_t)kNBK * 256 * 4);
  int* bo_u   = (int*)carve((size_t)kNBK * 256 * 4);
  int* base_i = (int*)carve(257 * 4);
  int* base_u = (int*)carve(257 * 4);
  unsigned* packed_i = (unsigned*)carve((size_t)kE * 4);
  unsigned* packed_u = (unsigned*)carve((size_t)kE * 4);
  int* col_i    = (int*)carve((size_t)(kE + 4) * 4);
  int* col_u    = (int*)carve((size_t)(kE + 4) * 4);
  int* rowptr_i = (int*)carve((size_t)(kNI + 1) * 4);
  int* rowptr_u = (int*)carve((size_t)(kNU + 1) * 4);

  int cvtN = (kNU * kC + kNI * kC) / 4;
  cvt_kernel<<<(cvtN + 255) / 256, 256, 0, stream>>>(x_user, x_item, fu[0], fi[0]);
  prep_w_kernel<<<512, 256, 0, stream>>>(w_rel, w_root, wcat);

  binA_kernel<<<2 * kNBK, 256, 0, stream>>>(e_ui_dst, e_iu_dst, bh_i, bh_u);
  binB_kernel<<<2, 256, 0, stream>>>(bh_i, bo_i, base_i, bh_u, bo_u, base_u);
  binC_kernel<<<2 * kNBK, 256, 0, stream>>>(e_ui_src, e_ui_dst, bo_i, base_i, packed_i,
                                            e_iu_src, e_iu_dst, bo_u, base_u, packed_u);
  binD_kernel<<<392, 256, 0, stream>>>(packed_i, base_i, col_i, rowptr_i,
                                       packed_u, base_u, col_u, rowptr_u);
  // zero-pad col arrays so pull3's 4-wide index over-reads stay safe
  hipMemsetAsync(col_i + kE, 0, 16, stream);
  hipMemsetAsync(col_u + kE, 0, 16, stream);

  int nbi_p = (kNI + 15) / 16;       // 3125
  int nbu_p = (kNU + 15) / 16;       // 6250
  int nbi_g = (kNI + 127) / 128;     // 391
  int nbu_g = (kNU + 127) / 128;     // 782

  int cur = 0;
  for (int l = 0; l < 2; ++l) {
    pull3_kernel<<<nbi_p + nbu_p, 256, 0, stream>>>(rowptr_i, col_i, fu[cur], agg_i,
                                                    rowptr_u, col_u, fi[cur], agg_u, nbi_p);
    gemm2_kernel<<<nbi_g + nbu_g, 256, 0, stream>>>(
        nbi_g,
        agg_i, fi[cur], wcat + (size_t)(l * 2 + 0) * 128 * 256,
        bvec + (size_t)(l * 2 + 0) * kC, ln_g + (size_t)(l * 2 + 1) * kC,
        ln_b + (size_t)(l * 2 + 1) * kC, fi[1 - cur],
        agg_u, fu[cur], wcat + (size_t)(l * 2 + 1) * 128 * 256,
        bvec + (size_t)(l * 2 + 1) * kC, ln_g + (size_t)(l * 2 + 0) * kC,
        ln_b + (size_t)(l * 2 + 0) * kC, fu[1 - cur]);
    cur ^= 1;
  }

  head_kernel<<<(kB + 3) / 4, 256, 0, stream>>>(fu[cur], lin_w, lin_b, (float*)d_out);
}